// Round 4
// baseline (863.203 us; speedup 1.0000x reference)
//
#include <hip/hip_runtime.h>

constexpr float BN_EPS = 1e-5f;

typedef __attribute__((ext_vector_type(8))) short bf16x8;
typedef __attribute__((ext_vector_type(4))) float f32x4;

__device__ __forceinline__ float4 ld4(const float* p) { return *(const float4*)p; }
__device__ __forceinline__ unsigned short f2bf(float x) {
  union { float f; unsigned u; } c; c.f = x;
  unsigned r = (c.u + 0x7fffu + ((c.u >> 16) & 1u)) >> 16;
  return (unsigned short)r;
}
__device__ __forceinline__ float bf1(unsigned short h) {
  union { unsigned i; float f; } a; a.i = ((unsigned)h) << 16; return a.f;
}
__device__ __forceinline__ float2 bf2(unsigned u) {
  union { unsigned i; float f; } lo, hi;
  lo.i = u << 16; hi.i = u & 0xffff0000u;
  return make_float2(lo.f, hi.f);
}
// packed f32->bf16 (RNE), 1 instr for 2 values
__device__ __forceinline__ unsigned pk_bf16(float lo, float hi) {
  unsigned r;
  asm("v_cvt_pk_bf16_f32 %0, %1, %2" : "=v"(r) : "v"(lo), "v"(hi));
  return r;
}

// ---------------- CSR build ----------------
__global__ void hist_kernel(const int* __restrict__ dst, int E, int* __restrict__ deg) {
  int e = blockIdx.x * 256 + threadIdx.x;
  if (e < E) atomicAdd(&deg[dst[e]], 1);
}

__global__ __launch_bounds__(1024) void scan_blocks_kernel(const int* __restrict__ deg, int n,
                                                           int* __restrict__ off, int* __restrict__ bsum) {
  __shared__ int lds[1024];
  int i = blockIdx.x * 1024 + threadIdx.x;
  int v = (i < n) ? deg[i] : 0;
  lds[threadIdx.x] = v;
  __syncthreads();
  for (int s = 1; s < 1024; s <<= 1) {
    int t = (threadIdx.x >= (unsigned)s) ? lds[threadIdx.x - s] : 0;
    __syncthreads();
    lds[threadIdx.x] += t;
    __syncthreads();
  }
  if (i < n) off[i] = lds[threadIdx.x] - v;
  if (threadIdx.x == 1023) bsum[blockIdx.x] = lds[1023];
}

__global__ void scan_sums_kernel(int* __restrict__ bsum, int nb) {
  int carry = 0;
  for (int base = 0; base < nb; base += 64) {
    int l = base + (int)threadIdx.x;
    int orig = (l < nb) ? bsum[l] : 0;
    int v = orig;
    for (int s = 1; s < 64; s <<= 1) {
      int t = __shfl_up(v, s);
      if ((int)threadIdx.x >= s) v += t;
    }
    if (l < nb) bsum[l] = carry + v - orig;
    carry += __shfl(v, 63);
  }
}

__global__ __launch_bounds__(1024) void scan_add_kernel(const int* __restrict__ bsum, int n,
                                                        int* __restrict__ off, int* __restrict__ cur) {
  int i = blockIdx.x * 1024 + threadIdx.x;
  if (i < n) {
    int o = off[i] + bsum[blockIdx.x];
    off[i] = o;
    cur[i] = o;
  }
}

__global__ void fill_kernel(const int* __restrict__ src, const int* __restrict__ dst, int E,
                            int* __restrict__ cur, int* __restrict__ elist) {
  int e = blockIdx.x * 256 + threadIdx.x;
  if (e < E) {
    int p = atomicAdd(&cur[dst[e]], 1);
    elist[p] = src[e];
  }
}

// ---------------- node projection: LDS-tiled GEMM ----------------
template <int K, bool BN, int MODE>
__global__ __launch_bounds__(256) void proj2_kernel(
    const float* __restrict__ X,
    const float* __restrict__ Wa, int lda, int koffa,
    const float* __restrict__ Wb, int ldb, int koffb,
    const float* __restrict__ scale, const float* __restrict__ shift,
    void* __restrict__ outA, void* __restrict__ outB, int n) {
  constexpr int KP = K + 4;
  __shared__ alignas(16) float ws[64 * KP];
  __shared__ alignas(16) float xs[64 * KP];
  const int ob = blockIdx.y;
  const float* W = ob ? Wb : Wa;
  const int ld = ob ? ldb : lda;
  const int koff = ob ? koffb : koffa;

  for (int idx = threadIdx.x; idx < 64 * K; idx += 256) {
    int o = idx / K, k = idx - o * K;
    ws[o * KP + k] = W[o * ld + koff + k];
  }
  int nb = blockIdx.x * 64;
  for (int idx = threadIdx.x; idx < 64 * K; idx += 256) {
    int nl = idx / K, k = idx - nl * K;
    int node = nb + nl;
    float v = (node < n) ? X[(size_t)node * K + k] : 0.f;
    if (BN) v = fmaxf(fmaf(v, scale[k], shift[k]), 0.f);
    xs[nl * KP + k] = v;
  }
  __syncthreads();

  int ng = threadIdx.x >> 4;
  int og = threadIdx.x & 15;
  float acc[4][4];
#pragma unroll
  for (int i = 0; i < 4; ++i)
#pragma unroll
    for (int j = 0; j < 4; ++j) acc[i][j] = 0.f;

  const float* xp = xs + (ng * 4) * KP;
  const float* wp = ws + og * KP;
#pragma unroll 2
  for (int k4 = 0; k4 < K / 4; ++k4) {
    float4 xv[4];
#pragma unroll
    for (int i = 0; i < 4; ++i) xv[i] = ld4(xp + i * KP + k4 * 4);
#pragma unroll
    for (int j = 0; j < 4; ++j) {
      float4 wv = ld4(wp + (j * 16) * KP + k4 * 4);
#pragma unroll
      for (int i = 0; i < 4; ++i) {
        acc[i][j] = fmaf(xv[i].x, wv.x, acc[i][j]);
        acc[i][j] = fmaf(xv[i].y, wv.y, acc[i][j]);
        acc[i][j] = fmaf(xv[i].z, wv.z, acc[i][j]);
        acc[i][j] = fmaf(xv[i].w, wv.w, acc[i][j]);
      }
    }
  }

#pragma unroll
  for (int i = 0; i < 4; ++i) {
    int node = nb + ng * 4 + i;
    if (node < n) {
#pragma unroll
      for (int j = 0; j < 4; ++j) {
        int col = j * 16 + og;
        float v = acc[i][j];
        if (MODE == 0) {
          if (ob == 0) ((unsigned short*)outA)[(size_t)node * 64 + col] = f2bf(v);
          else         ((float*)outB)[(size_t)node * 64 + col] = v;
        } else {
          ((unsigned short*)outA)[(size_t)node * 128 + ob * 64 + col] = f2bf(v);
        }
      }
    }
  }
}

// ---------------- aggregation ----------------
__global__ __launch_bounds__(256) void agg_kernel(
    const unsigned short* __restrict__ Pm, const float* __restrict__ Xr,
    const int* __restrict__ off, const int* __restrict__ deg,
    const int* __restrict__ elist, const float* __restrict__ bl,
    float* __restrict__ HP, int n) {
  int node = blockIdx.x * 4 + (threadIdx.x >> 6);
  if (node >= n) return;
  int c = threadIdx.x & 63;
  int d = deg[node];
  int o = off[node];
  float a0 = 0.f, a1 = 0.f, a2 = 0.f, a3 = 0.f;
  float a4 = 0.f, a5 = 0.f, a6 = 0.f, a7 = 0.f;
  int j = 0;
  for (; j + 8 <= d; j += 8) {
    int s0 = elist[o + j + 0], s1 = elist[o + j + 1], s2 = elist[o + j + 2], s3 = elist[o + j + 3];
    int s4 = elist[o + j + 4], s5 = elist[o + j + 5], s6 = elist[o + j + 6], s7 = elist[o + j + 7];
    a0 += bf1(Pm[(size_t)s0 * 64 + c]);
    a1 += bf1(Pm[(size_t)s1 * 64 + c]);
    a2 += bf1(Pm[(size_t)s2 * 64 + c]);
    a3 += bf1(Pm[(size_t)s3 * 64 + c]);
    a4 += bf1(Pm[(size_t)s4 * 64 + c]);
    a5 += bf1(Pm[(size_t)s5 * 64 + c]);
    a6 += bf1(Pm[(size_t)s6 * 64 + c]);
    a7 += bf1(Pm[(size_t)s7 * 64 + c]);
  }
  for (; j < d; ++j) a0 += bf1(Pm[(size_t)elist[o + j] * 64 + c]);
  float acc = ((a0 + a1) + (a2 + a3)) + ((a4 + a5) + (a6 + a7));
  float agg = acc / (float)(d > 0 ? d : 1);
  HP[(size_t)node * 64 + c] = agg + bl[c] + Xr[(size_t)node * 64 + c];
}

// ---------------- BN statistics ----------------
__global__ __launch_bounds__(256) void stats_kernel(const float* __restrict__ HP, int n,
                                                    float* __restrict__ partials) {
  int c = threadIdx.x & 63;
  int r0 = blockIdx.x * 4 + (threadIdx.x >> 6);
  float s = 0.f, q = 0.f;
  for (int i = r0; i < n; i += 1024) {
    float v = HP[(size_t)i * 64 + c];
    s += v; q += v * v;
  }
  __shared__ float ls[256], lq[256];
  ls[threadIdx.x] = s; lq[threadIdx.x] = q;
  __syncthreads();
  if (threadIdx.x < 64) {
    s = ls[threadIdx.x] + ls[threadIdx.x + 64] + ls[threadIdx.x + 128] + ls[threadIdx.x + 192];
    q = lq[threadIdx.x] + lq[threadIdx.x + 64] + lq[threadIdx.x + 128] + lq[threadIdx.x + 192];
    partials[blockIdx.x * 128 + c] = s;
    partials[blockIdx.x * 128 + 64 + c] = q;
  }
}

__global__ void bn_finalize_kernel(const float* __restrict__ partials, int nblk, int n,
                                   const float* __restrict__ g, const float* __restrict__ be,
                                   float* __restrict__ scale, float* __restrict__ shift) {
  int c = threadIdx.x;  // 64 threads
  float s = 0.f, q = 0.f;
  for (int b = 0; b < nblk; ++b) { s += partials[b * 128 + c]; q += partials[b * 128 + 64 + c]; }
  float mean = s / (float)n;
  float var = q / (float)n - mean * mean;
  float sc = g[c] * rsqrtf(var + BN_EPS);
  scale[c] = sc;
  shift[c] = be[c] - mean * sc;
}

// ---------------- Dte[t][o] = bm1[o] + sum_k Wm1[o][144+k]*temb[t][k] ----------------
__global__ void dte_kernel(const float* __restrict__ Wm1, const float* __restrict__ temb,
                           const float* __restrict__ bm1, float* __restrict__ Dte) {
  int t = threadIdx.x >> 6, o = threadIdx.x & 63;  // 1024 threads
  float acc = bm1[o];
#pragma unroll
  for (int k = 0; k < 8; ++k) acc = fmaf(Wm1[o * 152 + 144 + k], temb[t * 8 + k], acc);
  Dte[t * 64 + o] = acc;
}

// ---------------- fused edge MLP via MFMA ----------------
// Block = 128 edges, 2 waves; wave w owns edges [w*64, w*64+64).
// z1[e][o]  = relu( uvsum[e][o] + sum_k ea[e][k]*Cw[k][o] )   (uvsum = u+v+Dte[t], incl bm1)
// z2[e][j]  = relu( bm2[j] + sum_o z1[e][o]*Wm2[j][o] )
// out[e][c] = bm3[c] + sum_j z2[e][j]*Wm3[c][j]
// MFMA 16x16x32 bf16; fragment maps (m89): C/D col=lane&15,row=(lane>>4)*4+reg;
// A row=lane&15,k=(lane>>4)*8+j from [M][K]; B col=lane&15,k likewise from [N][K].
__global__ __launch_bounds__(128) void edge_mfma_kernel(
    const unsigned short* __restrict__ UVb, const int* __restrict__ ei,
    const float* __restrict__ eattr, const int* __restrict__ tix,
    const float* __restrict__ Dte,
    const float* __restrict__ Wm1, const float* __restrict__ Wm2,
    const float* __restrict__ bm2, const float* __restrict__ Wm3,
    const float* __restrict__ bm3, float* __restrict__ out, int E) {
  constexpr int UVP = 72;   // pitch (elems) of uvsum tile, 144B rows: 2-way bank alias max
  constexpr int A1P = 40;   // pitch of A1 (ea|pad) tile, 80B rows
  constexpr int Z1P = 72;   // pitch of z1 tile
  constexpr int B1P = 40;   // pitch of B1^T (Cw) tile
  constexpr int W2P = 72;   // pitch of W2 tile [32][64]
  __shared__ alignas(16) unsigned short uvs[128 * UVP];
  __shared__ alignas(16) unsigned short a1s[128 * A1P];
  __shared__ alignas(16) unsigned short z1s[128 * Z1P];
  __shared__ alignas(16) unsigned short b1s[64 * B1P];
  __shared__ alignas(16) unsigned short w2s[32 * W2P];
  __shared__ alignas(16) float dts[16 * 64];
  __shared__ alignas(8) float w3s[64];   // [col]{o0,o1}
  __shared__ float bm2s[32];

  const int tid = threadIdx.x;

  // ---- phase 0: shared tables ----
  for (int idx = tid; idx < 2048; idx += 128) {          // B1^T: [col][k] k<16 = Cw, else 0
    int col = idx >> 5, k = idx & 31;
    float v = (k < 16) ? Wm1[col * 152 + 128 + k] : 0.f;
    b1s[col * B1P + k] = f2bf(v);
  }
  for (int idx = tid; idx < 2048; idx += 128) {          // W2: [j][k]
    int j = idx >> 6, k = idx & 63;
    w2s[j * W2P + k] = f2bf(Wm2[j * 64 + k]);
  }
  for (int idx = tid; idx < 1024; idx += 128) dts[idx] = Dte[idx];
  if (tid < 32) {
    w3s[tid * 2] = Wm3[tid];
    w3s[tid * 2 + 1] = Wm3[32 + tid];
    bm2s[tid] = bm2[tid];
  }
  __syncthreads();

  // ---- phase 1: per-thread staging (1 edge each) ----
  const int e = blockIdx.x * 128 + tid;
  unsigned short* uvrow = &uvs[tid * UVP];
  unsigned short* a1row = &a1s[tid * A1P];
  if (e < E) {
    int s = ei[e], d = ei[E + e], t = tix[e];
    const uint4* up = (const uint4*)(UVb + (size_t)s * 128);
    const uint4* vp = (const uint4*)(UVb + (size_t)d * 128 + 64);
    const float* eap = eattr + (size_t)e * 16;
    uint4 ur[8], vr[8];
#pragma unroll
    for (int q = 0; q < 8; ++q) ur[q] = up[q];
#pragma unroll
    for (int q = 0; q < 8; ++q) vr[q] = vp[q];
    float4 e0 = ld4(eap), e1 = ld4(eap + 4), e2 = ld4(eap + 8), e3 = ld4(eap + 12);
    const float* dtp = &dts[t * 64];
#pragma unroll
    for (int q = 0; q < 8; ++q) {
      float4 d0 = ld4(dtp + q * 8);
      float4 d1 = ld4(dtp + q * 8 + 4);
      float2 u0 = bf2(ur[q].x), u1 = bf2(ur[q].y), u2 = bf2(ur[q].z), u3 = bf2(ur[q].w);
      float2 v0 = bf2(vr[q].x), v1 = bf2(vr[q].y), v2 = bf2(vr[q].z), v3 = bf2(vr[q].w);
      uint4 o;
      o.x = pk_bf16(u0.x + v0.x + d0.x, u0.y + v0.y + d0.y);
      o.y = pk_bf16(u1.x + v1.x + d0.z, u1.y + v1.y + d0.w);
      o.z = pk_bf16(u2.x + v2.x + d1.x, u2.y + v2.y + d1.y);
      o.w = pk_bf16(u3.x + v3.x + d1.z, u3.y + v3.y + d1.w);
      *(uint4*)(uvrow + q * 8) = o;
    }
    uint4 oa, ob, oz = make_uint4(0, 0, 0, 0);
    oa.x = pk_bf16(e0.x, e0.y); oa.y = pk_bf16(e0.z, e0.w);
    oa.z = pk_bf16(e1.x, e1.y); oa.w = pk_bf16(e1.z, e1.w);
    ob.x = pk_bf16(e2.x, e2.y); ob.y = pk_bf16(e2.z, e2.w);
    ob.z = pk_bf16(e3.x, e3.y); ob.w = pk_bf16(e3.z, e3.w);
    *(uint4*)(a1row + 0) = oa;
    *(uint4*)(a1row + 8) = ob;
    *(uint4*)(a1row + 16) = oz;
    *(uint4*)(a1row + 24) = oz;
  } else {
    uint4 oz = make_uint4(0, 0, 0, 0);
#pragma unroll
    for (int q = 0; q < 8; ++q) *(uint4*)(uvrow + q * 8) = oz;
#pragma unroll
    for (int q = 0; q < 4; ++q) *(uint4*)(a1row + q * 8) = oz;
  }
  __syncthreads();

  // ---- phase 2: z1 tiles (wave-local) ----
  const int w = tid >> 6, lane = tid & 63;
  const int g = lane >> 4, c16 = lane & 15;
  const int eb = w * 64;

  bf16x8 bfr[4];
#pragma unroll
  for (int ct = 0; ct < 4; ++ct)
    bfr[ct] = *(const bf16x8*)&b1s[(ct * 16 + c16) * B1P + g * 8];

#pragma unroll
  for (int et = 0; et < 4; ++et) {
    int r0 = eb + et * 16;
    bf16x8 a = *(const bf16x8*)&a1s[(r0 + c16) * A1P + g * 8];
    int rc = r0 + g * 4;
#pragma unroll
    for (int ct = 0; ct < 4; ++ct) {
      int col = ct * 16 + c16;
      f32x4 acc;
#pragma unroll
      for (int r = 0; r < 4; ++r) acc[r] = bf1(uvs[(rc + r) * UVP + col]);
      acc = __builtin_amdgcn_mfma_f32_16x16x32_bf16(a, bfr[ct], acc, 0, 0, 0);
#pragma unroll
      for (int r = 0; r < 2; ++r) {
        unsigned pk = pk_bf16(fmaxf(acc[2 * r], 0.f), fmaxf(acc[2 * r + 1], 0.f));
        z1s[(rc + 2 * r) * Z1P + col] = (unsigned short)pk;
        z1s[(rc + 2 * r + 1) * Z1P + col] = (unsigned short)(pk >> 16);
      }
    }
  }
  __syncthreads();

  // ---- phase 3: z2 + z3 ----
  bf16x8 bw[2][2];
#pragma unroll
  for (int jt = 0; jt < 2; ++jt)
#pragma unroll
    for (int ks = 0; ks < 2; ++ks)
      bw[jt][ks] = *(const bf16x8*)&w2s[(jt * 16 + c16) * W2P + ks * 32 + g * 8];
  float bm2c0 = bm2s[c16], bm2c1 = bm2s[16 + c16];
  float2 w3c0 = *(const float2*)&w3s[c16 * 2];
  float2 w3c1 = *(const float2*)&w3s[(16 + c16) * 2];
  const float b3a = bm3[0], b3b = bm3[1];

#pragma unroll
  for (int et = 0; et < 4; ++et) {
    int r0 = eb + et * 16;
    const unsigned short* zr = &z1s[(r0 + c16) * Z1P];
    bf16x8 a0 = *(const bf16x8*)(zr + g * 8);
    bf16x8 a1 = *(const bf16x8*)(zr + 32 + g * 8);
    f32x4 p0 = {0.f, 0.f, 0.f, 0.f}, p1 = {0.f, 0.f, 0.f, 0.f};
#pragma unroll
    for (int jt = 0; jt < 2; ++jt) {
      float bm = jt ? bm2c1 : bm2c0;
      float2 w3 = jt ? w3c1 : w3c0;
      f32x4 acc = {bm, bm, bm, bm};
      acc = __builtin_amdgcn_mfma_f32_16x16x32_bf16(a0, bw[jt][0], acc, 0, 0, 0);
      acc = __builtin_amdgcn_mfma_f32_16x16x32_bf16(a1, bw[jt][1], acc, 0, 0, 0);
#pragma unroll
      for (int r = 0; r < 4; ++r) {
        float z = fmaxf(acc[r], 0.f);
        p0[r] = fmaf(z, w3.x, p0[r]);
        p1[r] = fmaf(z, w3.y, p1[r]);
      }
    }
#pragma unroll
    for (int m = 1; m < 16; m <<= 1) {
#pragma unroll
      for (int r = 0; r < 4; ++r) {
        p0[r] += __shfl_xor(p0[r], m, 16);
        p1[r] += __shfl_xor(p1[r], m, 16);
      }
    }
    if (c16 == 0) {
      int eo = blockIdx.x * 128 + r0 + g * 4;
      if (eo + 3 < E) {
        float4 f0 = make_float4(p0[0] + b3a, p1[0] + b3b, p0[1] + b3a, p1[1] + b3b);
        float4 f1 = make_float4(p0[2] + b3a, p1[2] + b3b, p0[3] + b3a, p1[3] + b3b);
        *(float4*)&out[(size_t)eo * 2] = f0;
        *(float4*)&out[(size_t)eo * 2 + 4] = f1;
      } else {
#pragma unroll
        for (int r = 0; r < 4; ++r) {
          if (eo + r < E) {
            out[(size_t)(eo + r) * 2] = p0[r] + b3a;
            out[(size_t)(eo + r) * 2 + 1] = p1[r] + b3b;
          }
        }
      }
    }
  }
}

// ---------------- launcher ----------------
extern "C" void kernel_launch(void* const* d_in, const int* in_sizes, int n_in,
                              void* d_out, int out_size, void* d_ws, size_t ws_size,
                              hipStream_t stream) {
  const float* x    = (const float*)d_in[0];
  const int*   ei   = (const int*)d_in[1];
  const float* ea   = (const float*)d_in[2];
  const int*   tix  = (const int*)d_in[3];
  const float* temb = (const float*)d_in[4];
  const float* W1l  = (const float*)d_in[5];
  const float* b1l  = (const float*)d_in[6];
  const float* W1r  = (const float*)d_in[7];
  const float* g1   = (const float*)d_in[8];
  const float* be1  = (const float*)d_in[9];
  const float* W2l  = (const float*)d_in[10];
  const float* b2l  = (const float*)d_in[11];
  const float* W2r  = (const float*)d_in[12];
  const float* g2   = (const float*)d_in[13];
  const float* be2  = (const float*)d_in[14];
  const float* Wm1  = (const float*)d_in[15];
  const float* bm1  = (const float*)d_in[16];
  const float* Wm2  = (const float*)d_in[17];
  const float* bm2  = (const float*)d_in[18];
  const float* Wm3  = (const float*)d_in[19];
  const float* bm3  = (const float*)d_in[20];
  float* out = (float*)d_out;

  const int N = in_sizes[0] / 128;
  const int E = in_sizes[3];

  char* w = (char*)d_ws;
  auto alloc = [&](size_t bytes) -> char* {
    char* p = w;
    w += (bytes + 255) & ~(size_t)255;
    return p;
  };
  int* deg   = (int*)alloc((size_t)N * 4);
  int* off   = (int*)alloc((size_t)(N + 1) * 4);
  int* cur   = (int*)alloc((size_t)N * 4);
  int* elist = (int*)alloc((size_t)E * 4);
  unsigned short* Pm  = (unsigned short*)alloc((size_t)N * 64 * 2);   // bf16 msg table
  float*          Xr  = (float*)alloc((size_t)N * 64 * 4);            // f32 lin_r part
  unsigned short* UVb = (unsigned short*)alloc((size_t)N * 128 * 2);  // bf16 u|v table
  float* HP       = (float*)alloc((size_t)N * 64 * 4);
  float* partials = (float*)alloc(256 * 128 * 4);
  float* sc1 = (float*)alloc(64 * 4);
  float* sh1 = (float*)alloc(64 * 4);
  float* sc2 = (float*)alloc(64 * 4);
  float* sh2 = (float*)alloc(64 * 4);
  float* Dte = (float*)alloc(16 * 64 * 4);
  int* bsum  = (int*)alloc(256 * 4);

  const int* srcp = ei;
  const int* dstp = ei + E;

  int eb = (E + 255) / 256;
  int nb4 = (N + 3) / 4;
  int nb64 = (N + 63) / 64;
  int sb = (N + 1023) / 1024;

  // CSR build (shared by both SAGE layers)
  hipMemsetAsync(deg, 0, (size_t)N * 4, stream);
  hipLaunchKernelGGL(hist_kernel, dim3(eb), dim3(256), 0, stream, dstp, E, deg);
  hipLaunchKernelGGL(scan_blocks_kernel, dim3(sb), dim3(1024), 0, stream, deg, N, off, bsum);
  hipLaunchKernelGGL(scan_sums_kernel, dim3(1), dim3(64), 0, stream, bsum, sb);
  hipLaunchKernelGGL(scan_add_kernel, dim3(sb), dim3(1024), 0, stream, bsum, N, off, cur);
  hipLaunchKernelGGL(fill_kernel, dim3(eb), dim3(256), 0, stream, srcp, dstp, E, cur, elist);

  // ---- SAGE layer 1 ----
  hipLaunchKernelGGL((proj2_kernel<128, false, 0>), dim3(nb64, 2), dim3(256), 0, stream,
                     x, W1l, 128, 0, W1r, 128, 0, (const float*)nullptr, (const float*)nullptr,
                     (void*)Pm, (void*)Xr, N);
  hipLaunchKernelGGL(agg_kernel, dim3(nb4), dim3(256), 0, stream, Pm, Xr, off, deg, elist, b1l, HP, N);
  hipLaunchKernelGGL(stats_kernel, dim3(256), dim3(256), 0, stream, HP, N, partials);
  hipLaunchKernelGGL(bn_finalize_kernel, dim3(1), dim3(64), 0, stream, partials, 256, N, g1, be1, sc1, sh1);

  // ---- SAGE layer 2 (BN1+relu fused into projection load) ----
  hipLaunchKernelGGL((proj2_kernel<64, true, 0>), dim3(nb64, 2), dim3(256), 0, stream,
                     HP, W2l, 64, 0, W2r, 64, 0, sc1, sh1, (void*)Pm, (void*)Xr, N);
  hipLaunchKernelGGL(agg_kernel, dim3(nb4), dim3(256), 0, stream, Pm, Xr, off, deg, elist, b2l, HP, N);
  hipLaunchKernelGGL(stats_kernel, dim3(256), dim3(256), 0, stream, HP, N, partials);
  hipLaunchKernelGGL(bn_finalize_kernel, dim3(1), dim3(64), 0, stream, partials, 256, N, g2, be2, sc2, sh2);

  // ---- u/v node precompute ----
  hipLaunchKernelGGL((proj2_kernel<64, true, 1>), dim3(nb64, 2), dim3(256), 0, stream,
                     HP, Wm1, 152, 0, Wm1, 152, 64, sc2, sh2, (void*)UVb, (void*)nullptr, N);
  hipLaunchKernelGGL(dte_kernel, dim3(1), dim3(1024), 0, stream, Wm1, temb, bm1, Dte);

  // ---- fused edge MLP (MFMA) ----
  int ebm = (E + 127) / 128;
  hipLaunchKernelGGL(edge_mfma_kernel, dim3(ebm), dim3(128), 0, stream,
                     UVb, ei, ea, tix, Dte, Wm1, Wm2, bm2, Wm3, bm3, out, E);
}

// Round 5
// 711.325 us; speedup vs baseline: 1.2135x; 1.2135x over previous
//
#include <hip/hip_runtime.h>

constexpr float BN_EPS = 1e-5f;

typedef __attribute__((ext_vector_type(8))) short bf16x8;
typedef __attribute__((ext_vector_type(4))) float f32x4;

__device__ __forceinline__ float4 ld4(const float* p) { return *(const float4*)p; }
__device__ __forceinline__ unsigned short f2bf(float x) {
  union { float f; unsigned u; } c; c.f = x;
  unsigned r = (c.u + 0x7fffu + ((c.u >> 16) & 1u)) >> 16;
  return (unsigned short)r;
}
__device__ __forceinline__ float bf1(unsigned short h) {
  union { unsigned i; float f; } a; a.i = ((unsigned)h) << 16; return a.f;
}
__device__ __forceinline__ float2 bf2(unsigned u) {
  union { unsigned i; float f; } lo, hi;
  lo.i = u << 16; hi.i = u & 0xffff0000u;
  return make_float2(lo.f, hi.f);
}
// packed f32->bf16 (RNE), 1 instr for 2 values
__device__ __forceinline__ unsigned pk_bf16(float lo, float hi) {
  unsigned r;
  asm("v_cvt_pk_bf16_f32 %0, %1, %2" : "=v"(r) : "v"(lo), "v"(hi));
  return r;
}

// ---------------- CSR build ----------------
__global__ void hist_kernel(const int* __restrict__ dst, int E, int* __restrict__ deg) {
  int e = blockIdx.x * 256 + threadIdx.x;
  if (e < E) atomicAdd(&deg[dst[e]], 1);
}

__global__ __launch_bounds__(1024) void scan_blocks_kernel(const int* __restrict__ deg, int n,
                                                           int* __restrict__ off, int* __restrict__ bsum) {
  __shared__ int lds[1024];
  int i = blockIdx.x * 1024 + threadIdx.x;
  int v = (i < n) ? deg[i] : 0;
  lds[threadIdx.x] = v;
  __syncthreads();
  for (int s = 1; s < 1024; s <<= 1) {
    int t = (threadIdx.x >= (unsigned)s) ? lds[threadIdx.x - s] : 0;
    __syncthreads();
    lds[threadIdx.x] += t;
    __syncthreads();
  }
  if (i < n) off[i] = lds[threadIdx.x] - v;
  if (threadIdx.x == 1023) bsum[blockIdx.x] = lds[1023];
}

__global__ void scan_sums_kernel(int* __restrict__ bsum, int nb) {
  int carry = 0;
  for (int base = 0; base < nb; base += 64) {
    int l = base + (int)threadIdx.x;
    int orig = (l < nb) ? bsum[l] : 0;
    int v = orig;
    for (int s = 1; s < 64; s <<= 1) {
      int t = __shfl_up(v, s);
      if ((int)threadIdx.x >= s) v += t;
    }
    if (l < nb) bsum[l] = carry + v - orig;
    carry += __shfl(v, 63);
  }
}

__global__ __launch_bounds__(1024) void scan_add_kernel(const int* __restrict__ bsum, int n,
                                                        int* __restrict__ off, int* __restrict__ cur) {
  int i = blockIdx.x * 1024 + threadIdx.x;
  if (i < n) {
    int o = off[i] + bsum[blockIdx.x];
    off[i] = o;
    cur[i] = o;
  }
}

__global__ void fill_kernel(const int* __restrict__ src, const int* __restrict__ dst, int E,
                            int* __restrict__ cur, int* __restrict__ elist) {
  int e = blockIdx.x * 256 + threadIdx.x;
  if (e < E) {
    int p = atomicAdd(&cur[dst[e]], 1);
    elist[p] = src[e];
  }
}

// ---------------- node projection: LDS-tiled GEMM ----------------
template <int K, bool BN, int MODE>
__global__ __launch_bounds__(256) void proj2_kernel(
    const float* __restrict__ X,
    const float* __restrict__ Wa, int lda, int koffa,
    const float* __restrict__ Wb, int ldb, int koffb,
    const float* __restrict__ scale, const float* __restrict__ shift,
    void* __restrict__ outA, void* __restrict__ outB, int n) {
  constexpr int KP = K + 4;
  __shared__ alignas(16) float ws[64 * KP];
  __shared__ alignas(16) float xs[64 * KP];
  const int ob = blockIdx.y;
  const float* W = ob ? Wb : Wa;
  const int ld = ob ? ldb : lda;
  const int koff = ob ? koffb : koffa;

  for (int idx = threadIdx.x; idx < 64 * K; idx += 256) {
    int o = idx / K, k = idx - o * K;
    ws[o * KP + k] = W[o * ld + koff + k];
  }
  int nb = blockIdx.x * 64;
  for (int idx = threadIdx.x; idx < 64 * K; idx += 256) {
    int nl = idx / K, k = idx - nl * K;
    int node = nb + nl;
    float v = (node < n) ? X[(size_t)node * K + k] : 0.f;
    if (BN) v = fmaxf(fmaf(v, scale[k], shift[k]), 0.f);
    xs[nl * KP + k] = v;
  }
  __syncthreads();

  int ng = threadIdx.x >> 4;
  int og = threadIdx.x & 15;
  float acc[4][4];
#pragma unroll
  for (int i = 0; i < 4; ++i)
#pragma unroll
    for (int j = 0; j < 4; ++j) acc[i][j] = 0.f;

  const float* xp = xs + (ng * 4) * KP;
  const float* wp = ws + og * KP;
#pragma unroll 2
  for (int k4 = 0; k4 < K / 4; ++k4) {
    float4 xv[4];
#pragma unroll
    for (int i = 0; i < 4; ++i) xv[i] = ld4(xp + i * KP + k4 * 4);
#pragma unroll
    for (int j = 0; j < 4; ++j) {
      float4 wv = ld4(wp + (j * 16) * KP + k4 * 4);
#pragma unroll
      for (int i = 0; i < 4; ++i) {
        acc[i][j] = fmaf(xv[i].x, wv.x, acc[i][j]);
        acc[i][j] = fmaf(xv[i].y, wv.y, acc[i][j]);
        acc[i][j] = fmaf(xv[i].z, wv.z, acc[i][j]);
        acc[i][j] = fmaf(xv[i].w, wv.w, acc[i][j]);
      }
    }
  }

#pragma unroll
  for (int i = 0; i < 4; ++i) {
    int node = nb + ng * 4 + i;
    if (node < n) {
#pragma unroll
      for (int j = 0; j < 4; ++j) {
        int col = j * 16 + og;
        float v = acc[i][j];
        if (MODE == 0) {
          if (ob == 0) ((unsigned short*)outA)[(size_t)node * 64 + col] = f2bf(v);
          else         ((float*)outB)[(size_t)node * 64 + col] = v;
        } else {
          ((unsigned short*)outA)[(size_t)node * 128 + ob * 64 + col] = f2bf(v);
        }
      }
    }
  }
}

// ---------------- aggregation ----------------
__global__ __launch_bounds__(256) void agg_kernel(
    const unsigned short* __restrict__ Pm, const float* __restrict__ Xr,
    const int* __restrict__ off, const int* __restrict__ deg,
    const int* __restrict__ elist, const float* __restrict__ bl,
    float* __restrict__ HP, int n) {
  int node = blockIdx.x * 4 + (threadIdx.x >> 6);
  if (node >= n) return;
  int c = threadIdx.x & 63;
  int d = deg[node];
  int o = off[node];
  float a0 = 0.f, a1 = 0.f, a2 = 0.f, a3 = 0.f;
  float a4 = 0.f, a5 = 0.f, a6 = 0.f, a7 = 0.f;
  int j = 0;
  for (; j + 8 <= d; j += 8) {
    int s0 = elist[o + j + 0], s1 = elist[o + j + 1], s2 = elist[o + j + 2], s3 = elist[o + j + 3];
    int s4 = elist[o + j + 4], s5 = elist[o + j + 5], s6 = elist[o + j + 6], s7 = elist[o + j + 7];
    a0 += bf1(Pm[(size_t)s0 * 64 + c]);
    a1 += bf1(Pm[(size_t)s1 * 64 + c]);
    a2 += bf1(Pm[(size_t)s2 * 64 + c]);
    a3 += bf1(Pm[(size_t)s3 * 64 + c]);
    a4 += bf1(Pm[(size_t)s4 * 64 + c]);
    a5 += bf1(Pm[(size_t)s5 * 64 + c]);
    a6 += bf1(Pm[(size_t)s6 * 64 + c]);
    a7 += bf1(Pm[(size_t)s7 * 64 + c]);
  }
  for (; j < d; ++j) a0 += bf1(Pm[(size_t)elist[o + j] * 64 + c]);
  float acc = ((a0 + a1) + (a2 + a3)) + ((a4 + a5) + (a6 + a7));
  float agg = acc / (float)(d > 0 ? d : 1);
  HP[(size_t)node * 64 + c] = agg + bl[c] + Xr[(size_t)node * 64 + c];
}

// ---------------- BN statistics ----------------
__global__ __launch_bounds__(256) void stats_kernel(const float* __restrict__ HP, int n,
                                                    float* __restrict__ partials) {
  int c = threadIdx.x & 63;
  int r0 = blockIdx.x * 4 + (threadIdx.x >> 6);
  float s = 0.f, q = 0.f;
  for (int i = r0; i < n; i += 1024) {
    float v = HP[(size_t)i * 64 + c];
    s += v; q += v * v;
  }
  __shared__ float ls[256], lq[256];
  ls[threadIdx.x] = s; lq[threadIdx.x] = q;
  __syncthreads();
  if (threadIdx.x < 64) {
    s = ls[threadIdx.x] + ls[threadIdx.x + 64] + ls[threadIdx.x + 128] + ls[threadIdx.x + 192];
    q = lq[threadIdx.x] + lq[threadIdx.x + 64] + lq[threadIdx.x + 128] + lq[threadIdx.x + 192];
    partials[blockIdx.x * 128 + c] = s;
    partials[blockIdx.x * 128 + 64 + c] = q;
  }
}

__global__ void bn_finalize_kernel(const float* __restrict__ partials, int nblk, int n,
                                   const float* __restrict__ g, const float* __restrict__ be,
                                   float* __restrict__ scale, float* __restrict__ shift) {
  int c = threadIdx.x;  // 64 threads
  float s = 0.f, q = 0.f;
  for (int b = 0; b < nblk; ++b) { s += partials[b * 128 + c]; q += partials[b * 128 + 64 + c]; }
  float mean = s / (float)n;
  float var = q / (float)n - mean * mean;
  float sc = g[c] * rsqrtf(var + BN_EPS);
  scale[c] = sc;
  shift[c] = be[c] - mean * sc;
}

// ---------------- prep: pack edge-MLP weights to bf16 blob ----------------
// blob[0:2048)   = B1[o=64][k=32]: k<16 -> Cw[k][o]=Wm1[o][128+k]; k>=16 -> Dte[k-16][o] (incl bm1)
// blob[2048:4096) = W2[j=32][k=64]
__global__ void prep_kernel(const float* __restrict__ Wm1, const float* __restrict__ temb,
                            const float* __restrict__ bm1, const float* __restrict__ Wm2,
                            unsigned short* __restrict__ blob) {
  for (int i = threadIdx.x; i < 2048; i += 256) {
    int o = i >> 5, k = i & 31;
    float v;
    if (k < 16) {
      v = Wm1[o * 152 + 128 + k];
    } else {
      int t = k - 16;
      v = bm1[o];
#pragma unroll
      for (int q = 0; q < 8; ++q) v = fmaf(Wm1[o * 152 + 144 + q], temb[t * 8 + q], v);
    }
    blob[o * 32 + k] = f2bf(v);
  }
  for (int i = threadIdx.x; i < 2048; i += 256) {
    int j = i >> 6, k = i & 63;
    blob[2048 + j * 64 + k] = f2bf(Wm2[j * 64 + k]);
  }
}

// ---------------- fused edge MLP via MFMA, wave-local ----------------
// 64 edges per 64-thread (1-wave) block. Single 8.4KB LDS tile, col-major
// [64 cols/o][64 edges] pitch 66 shorts; uvsum overwritten in-place by z1.
// z1 = relu( (u[s]+v[d]) + [ea|onehot_t] @ [Cw;Dte]^T )   (K=32, Dte via one-hot)
// z2 = relu( bm2 + z1 @ W2^T );  out = bm3 + z2 @ W3^T
__global__ __launch_bounds__(64, 4) void edge_mfma_kernel(
    const unsigned short* __restrict__ UVb, const int* __restrict__ ei,
    const float* __restrict__ eattr, const int* __restrict__ tix,
    const unsigned short* __restrict__ blob,
    const float* __restrict__ Wm3, const float* __restrict__ bm2,
    const float* __restrict__ bm3, float* __restrict__ out, int E) {
  constexpr int P = 66;                       // shorts per column (33 words, odd -> bank spread)
  __shared__ unsigned short uvsT[64 * P];
  unsigned* uvsT32 = (unsigned*)uvsT;

  const int tid = threadIdx.x;
  const int g = tid >> 4, c16 = tid & 15;
  const int base = blockIdx.x * 64;

  // ---- B fragments straight from global (L2 broadcast, no LDS) ----
  bf16x8 bfr[4];
#pragma unroll
  for (int ct = 0; ct < 4; ++ct)
    bfr[ct] = *(const bf16x8*)(blob + (ct * 16 + c16) * 32 + g * 8);
  bf16x8 bw[2][2];
  const unsigned short* w2b = blob + 2048;
#pragma unroll
  for (int jt = 0; jt < 2; ++jt)
#pragma unroll
    for (int ks = 0; ks < 2; ++ks)
      bw[jt][ks] = *(const bf16x8*)(w2b + (jt * 16 + c16) * 64 + ks * 32 + g * 8);
  const float bm2c0 = bm2[c16], bm2c1 = bm2[16 + c16];
  const float2 w3c0 = make_float2(Wm3[c16], Wm3[32 + c16]);
  const float2 w3c1 = make_float2(Wm3[16 + c16], Wm3[48 + c16]);
  const float b3a = bm3[0], b3b = bm3[1];

  // ---- phase 1: stage uvsum = u[s]+v[d] (bf16) column-major, this thread = 1 edge ----
  const int e = base + tid;
  const bool live = e < E;
  const int s = live ? ei[e] : 0;
  const int d = live ? ei[E + e] : 0;
  const uint4* up = (const uint4*)(UVb + (size_t)s * 128);
  const uint4* vp = (const uint4*)(UVb + (size_t)d * 128 + 64);
#pragma unroll
  for (int h = 0; h < 2; ++h) {
    uint4 ur[4], vr[4];
#pragma unroll
    for (int q = 0; q < 4; ++q) { ur[q] = up[h * 4 + q]; vr[q] = vp[h * 4 + q]; }
#pragma unroll
    for (int q = 0; q < 4; ++q) {
      unsigned uw[4] = {ur[q].x, ur[q].y, ur[q].z, ur[q].w};
      unsigned vw[4] = {vr[q].x, vr[q].y, vr[q].z, vr[q].w};
      int colb = (h * 4 + q) * 8;
#pragma unroll
      for (int i = 0; i < 4; ++i) {
        float2 uu = bf2(uw[i]), vv = bf2(vw[i]);
        unsigned pk = live ? pk_bf16(uu.x + vv.x, uu.y + vv.y) : 0u;
        uvsT[(colb + 2 * i) * P + tid] = (unsigned short)pk;
        uvsT[(colb + 2 * i + 1) * P + tid] = (unsigned short)(pk >> 16);
      }
    }
  }
  __syncthreads();   // single wave: cheap; fences cross-lane LDS visibility

  // ---- phase 2: z1 tiles, in-place over uvsT ----
#pragma unroll
  for (int et = 0; et < 4; ++et) {
    int erow = base + et * 16 + c16;            // this lane's A-row edge
    bf16x8 a;
    if (g < 2) {                                // k = g*8+j in [0,16): ea
      if (erow < E) {
        const float* eap = eattr + (size_t)erow * 16 + g * 8;
        float4 f0 = ld4(eap), f1 = ld4(eap + 4);
        union { bf16x8 v; unsigned u[4]; } cc;
        cc.u[0] = pk_bf16(f0.x, f0.y); cc.u[1] = pk_bf16(f0.z, f0.w);
        cc.u[2] = pk_bf16(f1.x, f1.y); cc.u[3] = pk_bf16(f1.z, f1.w);
        a = cc.v;
      } else {
        a = bf16x8{0, 0, 0, 0, 0, 0, 0, 0};
      }
    } else {                                    // k-16 in [0,16): one-hot(t)
      int t = (erow < E) ? tix[erow] : -1;
      int kb = (g - 2) * 8;
      union { bf16x8 v; short s8[8]; } cc;
#pragma unroll
      for (int j = 0; j < 8; ++j) cc.s8[j] = (t == kb + j) ? (short)0x3F80 : (short)0;
      a = cc.v;
    }
    int rw = et * 8 + g * 2;                    // word offset of rows rc..rc+3 in a column
#pragma unroll
    for (int ct = 0; ct < 4; ++ct) {
      int cw = (ct * 16 + c16) * 33 + rw;
      unsigned lo = uvsT32[cw], hi = uvsT32[cw + 1];
      float2 l2 = bf2(lo), h2 = bf2(hi);
      f32x4 acc;
      acc[0] = l2.x; acc[1] = l2.y; acc[2] = h2.x; acc[3] = h2.y;
      acc = __builtin_amdgcn_mfma_f32_16x16x32_bf16(a, bfr[ct], acc, 0, 0, 0);
      uvsT32[cw]     = pk_bf16(fmaxf(acc[0], 0.f), fmaxf(acc[1], 0.f));
      uvsT32[cw + 1] = pk_bf16(fmaxf(acc[2], 0.f), fmaxf(acc[3], 0.f));
    }
  }
  __syncthreads();

  // ---- phase 3: z2 + z3 ----
#pragma unroll
  for (int et = 0; et < 4; ++et) {
    int ecol = et * 16 + c16;                   // this lane's A-row (edge, local)
    union { bf16x8 v; unsigned short s8[8]; } A0, A1;
#pragma unroll
    for (int j = 0; j < 8; ++j) {
      A0.s8[j] = uvsT[(g * 8 + j) * P + ecol];        // z1[e][k], k = g*8+j
      A1.s8[j] = uvsT[(32 + g * 8 + j) * P + ecol];   // k = 32+g*8+j
    }
    f32x4 p0 = {0.f, 0.f, 0.f, 0.f}, p1 = {0.f, 0.f, 0.f, 0.f};
#pragma unroll
    for (int jt = 0; jt < 2; ++jt) {
      float bm = jt ? bm2c1 : bm2c0;
      float2 w3 = jt ? w3c1 : w3c0;
      f32x4 acc = {bm, bm, bm, bm};
      acc = __builtin_amdgcn_mfma_f32_16x16x32_bf16(A0.v, bw[jt][0], acc, 0, 0, 0);
      acc = __builtin_amdgcn_mfma_f32_16x16x32_bf16(A1.v, bw[jt][1], acc, 0, 0, 0);
#pragma unroll
      for (int r = 0; r < 4; ++r) {
        float z = fmaxf(acc[r], 0.f);
        p0[r] = fmaf(z, w3.x, p0[r]);
        p1[r] = fmaf(z, w3.y, p1[r]);
      }
    }
#pragma unroll
    for (int m = 1; m < 16; m <<= 1) {
#pragma unroll
      for (int r = 0; r < 4; ++r) {
        p0[r] += __shfl_xor(p0[r], m, 16);
        p1[r] += __shfl_xor(p1[r], m, 16);
      }
    }
    if (c16 == 0) {
      int eo = base + et * 16 + g * 4;
      if (eo + 3 < E) {
        float4 f0 = make_float4(p0[0] + b3a, p1[0] + b3b, p0[1] + b3a, p1[1] + b3b);
        float4 f1 = make_float4(p0[2] + b3a, p1[2] + b3b, p0[3] + b3a, p1[3] + b3b);
        *(float4*)&out[(size_t)eo * 2] = f0;
        *(float4*)&out[(size_t)eo * 2 + 4] = f1;
      } else {
#pragma unroll
        for (int r = 0; r < 4; ++r) {
          if (eo + r < E) {
            out[(size_t)(eo + r) * 2] = p0[r] + b3a;
            out[(size_t)(eo + r) * 2 + 1] = p1[r] + b3b;
          }
        }
      }
    }
  }
}

// ---------------- launcher ----------------
extern "C" void kernel_launch(void* const* d_in, const int* in_sizes, int n_in,
                              void* d_out, int out_size, void* d_ws, size_t ws_size,
                              hipStream_t stream) {
  const float* x    = (const float*)d_in[0];
  const int*   ei   = (const int*)d_in[1];
  const float* ea   = (const float*)d_in[2];
  const int*   tix  = (const int*)d_in[3];
  const float* temb = (const float*)d_in[4];
  const float* W1l  = (const float*)d_in[5];
  const float* b1l  = (const float*)d_in[6];
  const float* W1r  = (const float*)d_in[7];
  const float* g1   = (const float*)d_in[8];
  const float* be1  = (const float*)d_in[9];
  const float* W2l  = (const float*)d_in[10];
  const float* b2l  = (const float*)d_in[11];
  const float* W2r  = (const float*)d_in[12];
  const float* g2   = (const float*)d_in[13];
  const float* be2  = (const float*)d_in[14];
  const float* Wm1  = (const float*)d_in[15];
  const float* bm1  = (const float*)d_in[16];
  const float* Wm2  = (const float*)d_in[17];
  const float* bm2  = (const float*)d_in[18];
  const float* Wm3  = (const float*)d_in[19];
  const float* bm3  = (const float*)d_in[20];
  float* out = (float*)d_out;

  const int N = in_sizes[0] / 128;
  const int E = in_sizes[3];

  char* w = (char*)d_ws;
  auto alloc = [&](size_t bytes) -> char* {
    char* p = w;
    w += (bytes + 255) & ~(size_t)255;
    return p;
  };
  int* deg   = (int*)alloc((size_t)N * 4);
  int* off   = (int*)alloc((size_t)(N + 1) * 4);
  int* cur   = (int*)alloc((size_t)N * 4);
  int* elist = (int*)alloc((size_t)E * 4);
  unsigned short* Pm  = (unsigned short*)alloc((size_t)N * 64 * 2);   // bf16 msg table
  float*          Xr  = (float*)alloc((size_t)N * 64 * 4);            // f32 lin_r part
  unsigned short* UVb = (unsigned short*)alloc((size_t)N * 128 * 2);  // bf16 u|v table
  float* HP       = (float*)alloc((size_t)N * 64 * 4);
  float* partials = (float*)alloc(256 * 128 * 4);
  float* sc1 = (float*)alloc(64 * 4);
  float* sh1 = (float*)alloc(64 * 4);
  float* sc2 = (float*)alloc(64 * 4);
  float* sh2 = (float*)alloc(64 * 4);
  unsigned short* blob = (unsigned short*)alloc(4096 * 2);
  int* bsum  = (int*)alloc(256 * 4);

  const int* srcp = ei;
  const int* dstp = ei + E;

  int eb = (E + 255) / 256;
  int nb4 = (N + 3) / 4;
  int nb64 = (N + 63) / 64;
  int sb = (N + 1023) / 1024;

  // CSR build (shared by both SAGE layers)
  hipMemsetAsync(deg, 0, (size_t)N * 4, stream);
  hipLaunchKernelGGL(hist_kernel, dim3(eb), dim3(256), 0, stream, dstp, E, deg);
  hipLaunchKernelGGL(scan_blocks_kernel, dim3(sb), dim3(1024), 0, stream, deg, N, off, bsum);
  hipLaunchKernelGGL(scan_sums_kernel, dim3(1), dim3(64), 0, stream, bsum, sb);
  hipLaunchKernelGGL(scan_add_kernel, dim3(sb), dim3(1024), 0, stream, bsum, N, off, cur);
  hipLaunchKernelGGL(fill_kernel, dim3(eb), dim3(256), 0, stream, srcp, dstp, E, cur, elist);

  // ---- SAGE layer 1 ----
  hipLaunchKernelGGL((proj2_kernel<128, false, 0>), dim3(nb64, 2), dim3(256), 0, stream,
                     x, W1l, 128, 0, W1r, 128, 0, (const float*)nullptr, (const float*)nullptr,
                     (void*)Pm, (void*)Xr, N);
  hipLaunchKernelGGL(agg_kernel, dim3(nb4), dim3(256), 0, stream, Pm, Xr, off, deg, elist, b1l, HP, N);
  hipLaunchKernelGGL(stats_kernel, dim3(256), dim3(256), 0, stream, HP, N, partials);
  hipLaunchKernelGGL(bn_finalize_kernel, dim3(1), dim3(64), 0, stream, partials, 256, N, g1, be1, sc1, sh1);

  // ---- SAGE layer 2 (BN1+relu fused into projection load) ----
  hipLaunchKernelGGL((proj2_kernel<64, true, 0>), dim3(nb64, 2), dim3(256), 0, stream,
                     HP, W2l, 64, 0, W2r, 64, 0, sc1, sh1, (void*)Pm, (void*)Xr, N);
  hipLaunchKernelGGL(agg_kernel, dim3(nb4), dim3(256), 0, stream, Pm, Xr, off, deg, elist, b2l, HP, N);
  hipLaunchKernelGGL(stats_kernel, dim3(256), dim3(256), 0, stream, HP, N, partials);
  hipLaunchKernelGGL(bn_finalize_kernel, dim3(1), dim3(64), 0, stream, partials, 256, N, g2, be2, sc2, sh2);

  // ---- u/v node precompute + weight packing ----
  hipLaunchKernelGGL((proj2_kernel<64, true, 1>), dim3(nb64, 2), dim3(256), 0, stream,
                     HP, Wm1, 152, 0, Wm1, 152, 64, sc2, sh2, (void*)UVb, (void*)nullptr, N);
  hipLaunchKernelGGL(prep_kernel, dim3(1), dim3(256), 0, stream, Wm1, temb, bm1, Wm2, blob);

  // ---- fused edge MLP (wave-local MFMA) ----
  int ebm = (E + 63) / 64;
  hipLaunchKernelGGL(edge_mfma_kernel, dim3(ebm), dim3(64), 0, stream,
                     UVb, ei, ea, tix, blob, Wm3, bm2, bm3, out, E);
}

// Round 6
// 697.850 us; speedup vs baseline: 1.2369x; 1.0193x over previous
//
#include <hip/hip_runtime.h>

constexpr float BN_EPS = 1e-5f;

typedef __attribute__((ext_vector_type(8))) short bf16x8;
typedef __attribute__((ext_vector_type(4))) float f32x4;

__device__ __forceinline__ float4 ld4(const float* p) { return *(const float4*)p; }
__device__ __forceinline__ unsigned short f2bf(float x) {
  union { float f; unsigned u; } c; c.f = x;
  unsigned r = (c.u + 0x7fffu + ((c.u >> 16) & 1u)) >> 16;
  return (unsigned short)r;
}
__device__ __forceinline__ float bf1(unsigned short h) {
  union { unsigned i; float f; } a; a.i = ((unsigned)h) << 16; return a.f;
}
__device__ __forceinline__ float2 bf2(unsigned u) {
  union { unsigned i; float f; } lo, hi;
  lo.i = u << 16; hi.i = u & 0xffff0000u;
  return make_float2(lo.f, hi.f);
}
// packed f32->bf16 (RNE), 1 instr for 2 values
__device__ __forceinline__ unsigned pk_bf16(float lo, float hi) {
  unsigned r;
  asm("v_cvt_pk_bf16_f32 %0, %1, %2" : "=v"(r) : "v"(lo), "v"(hi));
  return r;
}

// ---------------- CSR build ----------------
__global__ void hist_kernel(const int* __restrict__ dst, int E, int* __restrict__ deg) {
  int e = blockIdx.x * 256 + threadIdx.x;
  if (e < E) atomicAdd(&deg[dst[e]], 1);
}

__global__ __launch_bounds__(1024) void scan_blocks_kernel(const int* __restrict__ deg, int n,
                                                           int* __restrict__ off, int* __restrict__ bsum) {
  __shared__ int lds[1024];
  int i = blockIdx.x * 1024 + threadIdx.x;
  int v = (i < n) ? deg[i] : 0;
  lds[threadIdx.x] = v;
  __syncthreads();
  for (int s = 1; s < 1024; s <<= 1) {
    int t = (threadIdx.x >= (unsigned)s) ? lds[threadIdx.x - s] : 0;
    __syncthreads();
    lds[threadIdx.x] += t;
    __syncthreads();
  }
  if (i < n) off[i] = lds[threadIdx.x] - v;
  if (threadIdx.x == 1023) bsum[blockIdx.x] = lds[1023];
}

__global__ void scan_sums_kernel(int* __restrict__ bsum, int nb) {
  int carry = 0;
  for (int base = 0; base < nb; base += 64) {
    int l = base + (int)threadIdx.x;
    int orig = (l < nb) ? bsum[l] : 0;
    int v = orig;
    for (int s = 1; s < 64; s <<= 1) {
      int t = __shfl_up(v, s);
      if ((int)threadIdx.x >= s) v += t;
    }
    if (l < nb) bsum[l] = carry + v - orig;
    carry += __shfl(v, 63);
  }
}

__global__ __launch_bounds__(1024) void scan_add_kernel(const int* __restrict__ bsum, int n,
                                                        int* __restrict__ off, int* __restrict__ cur) {
  int i = blockIdx.x * 1024 + threadIdx.x;
  if (i < n) {
    int o = off[i] + bsum[blockIdx.x];
    off[i] = o;
    cur[i] = o;
  }
}

__global__ void fill_kernel(const int* __restrict__ src, const int* __restrict__ dst, int E,
                            int* __restrict__ cur, int* __restrict__ elist) {
  int e = blockIdx.x * 256 + threadIdx.x;
  if (e < E) {
    int p = atomicAdd(&cur[dst[e]], 1);
    elist[p] = src[e];
  }
}

// ---------------- node projection: LDS-tiled GEMM ----------------
template <int K, bool BN, int MODE>
__global__ __launch_bounds__(256) void proj2_kernel(
    const float* __restrict__ X,
    const float* __restrict__ Wa, int lda, int koffa,
    const float* __restrict__ Wb, int ldb, int koffb,
    const float* __restrict__ scale, const float* __restrict__ shift,
    void* __restrict__ outA, void* __restrict__ outB, int n) {
  constexpr int KP = K + 4;
  __shared__ alignas(16) float ws[64 * KP];
  __shared__ alignas(16) float xs[64 * KP];
  const int ob = blockIdx.y;
  const float* W = ob ? Wb : Wa;
  const int ld = ob ? ldb : lda;
  const int koff = ob ? koffb : koffa;

  for (int idx = threadIdx.x; idx < 64 * K; idx += 256) {
    int o = idx / K, k = idx - o * K;
    ws[o * KP + k] = W[o * ld + koff + k];
  }
  int nb = blockIdx.x * 64;
  for (int idx = threadIdx.x; idx < 64 * K; idx += 256) {
    int nl = idx / K, k = idx - nl * K;
    int node = nb + nl;
    float v = (node < n) ? X[(size_t)node * K + k] : 0.f;
    if (BN) v = fmaxf(fmaf(v, scale[k], shift[k]), 0.f);
    xs[nl * KP + k] = v;
  }
  __syncthreads();

  int ng = threadIdx.x >> 4;
  int og = threadIdx.x & 15;
  float acc[4][4];
#pragma unroll
  for (int i = 0; i < 4; ++i)
#pragma unroll
    for (int j = 0; j < 4; ++j) acc[i][j] = 0.f;

  const float* xp = xs + (ng * 4) * KP;
  const float* wp = ws + og * KP;
#pragma unroll 2
  for (int k4 = 0; k4 < K / 4; ++k4) {
    float4 xv[4];
#pragma unroll
    for (int i = 0; i < 4; ++i) xv[i] = ld4(xp + i * KP + k4 * 4);
#pragma unroll
    for (int j = 0; j < 4; ++j) {
      float4 wv = ld4(wp + (j * 16) * KP + k4 * 4);
#pragma unroll
      for (int i = 0; i < 4; ++i) {
        acc[i][j] = fmaf(xv[i].x, wv.x, acc[i][j]);
        acc[i][j] = fmaf(xv[i].y, wv.y, acc[i][j]);
        acc[i][j] = fmaf(xv[i].z, wv.z, acc[i][j]);
        acc[i][j] = fmaf(xv[i].w, wv.w, acc[i][j]);
      }
    }
  }

#pragma unroll
  for (int i = 0; i < 4; ++i) {
    int node = nb + ng * 4 + i;
    if (node < n) {
#pragma unroll
      for (int j = 0; j < 4; ++j) {
        int col = j * 16 + og;
        float v = acc[i][j];
        if (MODE == 0) {
          if (ob == 0) ((unsigned short*)outA)[(size_t)node * 64 + col] = f2bf(v);
          else         ((float*)outB)[(size_t)node * 64 + col] = v;
        } else {
          ((unsigned short*)outA)[(size_t)node * 128 + ob * 64 + col] = f2bf(v);
        }
      }
    }
  }
}

// ---------------- aggregation ----------------
__global__ __launch_bounds__(256) void agg_kernel(
    const unsigned short* __restrict__ Pm, const float* __restrict__ Xr,
    const int* __restrict__ off, const int* __restrict__ deg,
    const int* __restrict__ elist, const float* __restrict__ bl,
    float* __restrict__ HP, int n) {
  int node = blockIdx.x * 4 + (threadIdx.x >> 6);
  if (node >= n) return;
  int c = threadIdx.x & 63;
  int d = deg[node];
  int o = off[node];
  float a0 = 0.f, a1 = 0.f, a2 = 0.f, a3 = 0.f;
  float a4 = 0.f, a5 = 0.f, a6 = 0.f, a7 = 0.f;
  int j = 0;
  for (; j + 8 <= d; j += 8) {
    int s0 = elist[o + j + 0], s1 = elist[o + j + 1], s2 = elist[o + j + 2], s3 = elist[o + j + 3];
    int s4 = elist[o + j + 4], s5 = elist[o + j + 5], s6 = elist[o + j + 6], s7 = elist[o + j + 7];
    a0 += bf1(Pm[(size_t)s0 * 64 + c]);
    a1 += bf1(Pm[(size_t)s1 * 64 + c]);
    a2 += bf1(Pm[(size_t)s2 * 64 + c]);
    a3 += bf1(Pm[(size_t)s3 * 64 + c]);
    a4 += bf1(Pm[(size_t)s4 * 64 + c]);
    a5 += bf1(Pm[(size_t)s5 * 64 + c]);
    a6 += bf1(Pm[(size_t)s6 * 64 + c]);
    a7 += bf1(Pm[(size_t)s7 * 64 + c]);
  }
  for (; j < d; ++j) a0 += bf1(Pm[(size_t)elist[o + j] * 64 + c]);
  float acc = ((a0 + a1) + (a2 + a3)) + ((a4 + a5) + (a6 + a7));
  float agg = acc / (float)(d > 0 ? d : 1);
  HP[(size_t)node * 64 + c] = agg + bl[c] + Xr[(size_t)node * 64 + c];
}

// ---------------- BN statistics ----------------
__global__ __launch_bounds__(256) void stats_kernel(const float* __restrict__ HP, int n,
                                                    float* __restrict__ partials) {
  int c = threadIdx.x & 63;
  int r0 = blockIdx.x * 4 + (threadIdx.x >> 6);
  float s = 0.f, q = 0.f;
  for (int i = r0; i < n; i += 1024) {
    float v = HP[(size_t)i * 64 + c];
    s += v; q += v * v;
  }
  __shared__ float ls[256], lq[256];
  ls[threadIdx.x] = s; lq[threadIdx.x] = q;
  __syncthreads();
  if (threadIdx.x < 64) {
    s = ls[threadIdx.x] + ls[threadIdx.x + 64] + ls[threadIdx.x + 128] + ls[threadIdx.x + 192];
    q = lq[threadIdx.x] + lq[threadIdx.x + 64] + lq[threadIdx.x + 128] + lq[threadIdx.x + 192];
    partials[blockIdx.x * 128 + c] = s;
    partials[blockIdx.x * 128 + 64 + c] = q;
  }
}

__global__ void bn_finalize_kernel(const float* __restrict__ partials, int nblk, int n,
                                   const float* __restrict__ g, const float* __restrict__ be,
                                   float* __restrict__ scale, float* __restrict__ shift) {
  int c = threadIdx.x;  // 64 threads
  float s = 0.f, q = 0.f;
  for (int b = 0; b < nblk; ++b) { s += partials[b * 128 + c]; q += partials[b * 128 + 64 + c]; }
  float mean = s / (float)n;
  float var = q / (float)n - mean * mean;
  float sc = g[c] * rsqrtf(var + BN_EPS);
  scale[c] = sc;
  shift[c] = be[c] - mean * sc;
}

// ---------------- prep: pack edge-MLP weights to bf16 blob ----------------
// blob[0:2048)   = B1[o=64][k=32]: k<16 -> Cw[k][o]=Wm1[o][128+k]; k>=16 -> Dte[k-16][o] (incl bm1)
// blob[2048:4096) = W2[j=32][k=64]
__global__ void prep_kernel(const float* __restrict__ Wm1, const float* __restrict__ temb,
                            const float* __restrict__ bm1, const float* __restrict__ Wm2,
                            unsigned short* __restrict__ blob) {
  for (int i = threadIdx.x; i < 2048; i += 256) {
    int o = i >> 5, k = i & 31;
    float v;
    if (k < 16) {
      v = Wm1[o * 152 + 128 + k];
    } else {
      int t = k - 16;
      v = bm1[o];
#pragma unroll
      for (int q = 0; q < 8; ++q) v = fmaf(Wm1[o * 152 + 144 + q], temb[t * 8 + q], v);
    }
    blob[o * 32 + k] = f2bf(v);
  }
  for (int i = threadIdx.x; i < 2048; i += 256) {
    int j = i >> 6, k = i & 63;
    blob[2048 + j * 64 + k] = f2bf(Wm2[j * 64 + k]);
  }
}

// ---------------- fused edge MLP via MFMA, wave-local, zero-staging ----------------
// 64 edges per 64-thread (1-wave) block. LDS only holds the z1 tile (8.4KB),
// col-major [64 o][64 e] pitch 66 shorts.
// z1 = relu( [ea|onehot_t] @ [Cw;Dte]^T + I·u[s] + I·v[d] )   (u/v gathered
//   directly into A-fragments from global; identity B built in-register)
// z2 = relu( bm2 + z1 @ W2^T );  out = bm3 + z2 @ W3^T
__global__ __launch_bounds__(64, 4) void edge_mfma_kernel(
    const unsigned short* __restrict__ UVb, const int* __restrict__ ei,
    const float* __restrict__ eattr, const int* __restrict__ tix,
    const unsigned short* __restrict__ blob,
    const float* __restrict__ Wm3, const float* __restrict__ bm2,
    const float* __restrict__ bm3, float* __restrict__ out, int E) {
  constexpr int P = 66;                       // shorts per column (33 words, odd -> bank spread)
  __shared__ unsigned short z1T[64 * P];
  unsigned* z1T32 = (unsigned*)z1T;

  const int tid = threadIdx.x;
  const int g = tid >> 4, c16 = tid & 15;
  const int base = blockIdx.x * 64;

  // ---- B fragments straight from global (L2 broadcast, no LDS) ----
  bf16x8 bfr[4];
#pragma unroll
  for (int ct = 0; ct < 4; ++ct)
    bfr[ct] = *(const bf16x8*)(blob + (ct * 16 + c16) * 32 + g * 8);
  bf16x8 bw[2][2];
  const unsigned short* w2b = blob + 2048;
#pragma unroll
  for (int jt = 0; jt < 2; ++jt)
#pragma unroll
    for (int ks = 0; ks < 2; ++ks)
      bw[jt][ks] = *(const bf16x8*)(w2b + (jt * 16 + c16) * 64 + ks * 32 + g * 8);
  // identity B fragments: bi[h].s8[j] = (k_local==16h+c16) ? 1.0bf16 : 0
  union { bf16x8 v; short s8[8]; } bi0, bi1;
#pragma unroll
  for (int j = 0; j < 8; ++j) {
    bi0.s8[j] = (g * 8 + j == c16) ? (short)0x3F80 : (short)0;
    bi1.s8[j] = (g * 8 + j == 16 + c16) ? (short)0x3F80 : (short)0;
  }
  const float bm2c0 = bm2[c16], bm2c1 = bm2[16 + c16];
  const float2 w3c0 = make_float2(Wm3[c16], Wm3[32 + c16]);
  const float2 w3c1 = make_float2(Wm3[16 + c16], Wm3[48 + c16]);
  const float b3a = bm3[0], b3b = bm3[1];

  // ---- phase A: z1 tiles (u/v gathered straight into A-fragments) ----
#pragma unroll
  for (int et = 0; et < 4; ++et) {
    int erow = base + et * 16 + c16;            // this lane's A-row edge
    bool lv = erow < E;
    int s = lv ? ei[erow] : 0;
    int d = lv ? ei[E + erow] : 0;
    // A_eaoh: k<16 = ea, k>=16 = onehot(t)
    bf16x8 a_eaoh;
    if (g < 2) {
      if (lv) {
        const float* eap = eattr + (size_t)erow * 16 + g * 8;
        float4 f0 = ld4(eap), f1 = ld4(eap + 4);
        union { bf16x8 v; unsigned u[4]; } cc;
        cc.u[0] = pk_bf16(f0.x, f0.y); cc.u[1] = pk_bf16(f0.z, f0.w);
        cc.u[2] = pk_bf16(f1.x, f1.y); cc.u[3] = pk_bf16(f1.z, f1.w);
        a_eaoh = cc.v;
      } else {
        a_eaoh = bf16x8{0, 0, 0, 0, 0, 0, 0, 0};
      }
    } else {
      int t = lv ? tix[erow] : -1;
      int kb = (g - 2) * 8;
      union { bf16x8 v; short s8[8]; } cc;
#pragma unroll
      for (int j = 0; j < 8; ++j) cc.s8[j] = (t == kb + j) ? (short)0x3F80 : (short)0;
      a_eaoh = cc.v;
    }
    // u/v A-fragments: row e, k window w covers u-elems [32w,32w+32)
    const bf16x8* urow = (const bf16x8*)(UVb + (size_t)s * 128);
    const bf16x8* vrow = (const bf16x8*)(UVb + (size_t)d * 128);
    bf16x8 au0 = urow[g];         // u elems g*8..g*8+8      (window 0)
    bf16x8 au1 = urow[4 + g];     // u elems 32+g*8..        (window 1)
    bf16x8 av0 = vrow[8 + g];     // v elems g*8..           (window 0)
    bf16x8 av1 = vrow[12 + g];    // v elems 32+g*8..        (window 1)

#pragma unroll
    for (int ct = 0; ct < 4; ++ct) {
      f32x4 acc = {0.f, 0.f, 0.f, 0.f};
      acc = __builtin_amdgcn_mfma_f32_16x16x32_bf16(a_eaoh, bfr[ct], acc, 0, 0, 0);
      const bf16x8 au = (ct < 2) ? au0 : au1;
      const bf16x8 av = (ct < 2) ? av0 : av1;
      const bf16x8 bi = (ct & 1) ? bi1.v : bi0.v;
      acc = __builtin_amdgcn_mfma_f32_16x16x32_bf16(au, bi, acc, 0, 0, 0);
      acc = __builtin_amdgcn_mfma_f32_16x16x32_bf16(av, bi, acc, 0, 0, 0);
      int cw = (ct * 16 + c16) * 33 + et * 8 + g * 2;
      z1T32[cw]     = pk_bf16(fmaxf(acc[0], 0.f), fmaxf(acc[1], 0.f));
      z1T32[cw + 1] = pk_bf16(fmaxf(acc[2], 0.f), fmaxf(acc[3], 0.f));
    }
  }
  __syncthreads();   // single wave: orders LDS writes before reads

  // ---- phase B: z2 + z3 ----
#pragma unroll
  for (int et = 0; et < 4; ++et) {
    int ecol = et * 16 + c16;                   // this lane's A-row (edge, local)
    union { bf16x8 v; unsigned short s8[8]; } A0, A1;
#pragma unroll
    for (int j = 0; j < 8; ++j) {
      A0.s8[j] = z1T[(g * 8 + j) * P + ecol];        // z1[e][k], k = g*8+j
      A1.s8[j] = z1T[(32 + g * 8 + j) * P + ecol];   // k = 32+g*8+j
    }
    f32x4 p0 = {0.f, 0.f, 0.f, 0.f}, p1 = {0.f, 0.f, 0.f, 0.f};
#pragma unroll
    for (int jt = 0; jt < 2; ++jt) {
      float bm = jt ? bm2c1 : bm2c0;
      float2 w3 = jt ? w3c1 : w3c0;
      f32x4 acc = {bm, bm, bm, bm};
      acc = __builtin_amdgcn_mfma_f32_16x16x32_bf16(A0.v, bw[jt][0], acc, 0, 0, 0);
      acc = __builtin_amdgcn_mfma_f32_16x16x32_bf16(A1.v, bw[jt][1], acc, 0, 0, 0);
#pragma unroll
      for (int r = 0; r < 4; ++r) {
        float z = fmaxf(acc[r], 0.f);
        p0[r] = fmaf(z, w3.x, p0[r]);
        p1[r] = fmaf(z, w3.y, p1[r]);
      }
    }
#pragma unroll
    for (int m = 1; m < 16; m <<= 1) {
#pragma unroll
      for (int r = 0; r < 4; ++r) {
        p0[r] += __shfl_xor(p0[r], m, 16);
        p1[r] += __shfl_xor(p1[r], m, 16);
      }
    }
    if (c16 == 0) {
      int eo = base + et * 16 + g * 4;
      if (eo + 3 < E) {
        float4 f0 = make_float4(p0[0] + b3a, p1[0] + b3b, p0[1] + b3a, p1[1] + b3b);
        float4 f1 = make_float4(p0[2] + b3a, p1[2] + b3b, p0[3] + b3a, p1[3] + b3b);
        *(float4*)&out[(size_t)eo * 2] = f0;
        *(float4*)&out[(size_t)eo * 2 + 4] = f1;
      } else {
#pragma unroll
        for (int r = 0; r < 4; ++r) {
          if (eo + r < E) {
            out[(size_t)(eo + r) * 2] = p0[r] + b3a;
            out[(size_t)(eo + r) * 2 + 1] = p1[r] + b3b;
          }
        }
      }
    }
  }
}

// ---------------- launcher ----------------
extern "C" void kernel_launch(void* const* d_in, const int* in_sizes, int n_in,
                              void* d_out, int out_size, void* d_ws, size_t ws_size,
                              hipStream_t stream) {
  const float* x    = (const float*)d_in[0];
  const int*   ei   = (const int*)d_in[1];
  const float* ea   = (const float*)d_in[2];
  const int*   tix  = (const int*)d_in[3];
  const float* temb = (const float*)d_in[4];
  const float* W1l  = (const float*)d_in[5];
  const float* b1l  = (const float*)d_in[6];
  const float* W1r  = (const float*)d_in[7];
  const float* g1   = (const float*)d_in[8];
  const float* be1  = (const float*)d_in[9];
  const float* W2l  = (const float*)d_in[10];
  const float* b2l  = (const float*)d_in[11];
  const float* W2r  = (const float*)d_in[12];
  const float* g2   = (const float*)d_in[13];
  const float* be2  = (const float*)d_in[14];
  const float* Wm1  = (const float*)d_in[15];
  const float* bm1  = (const float*)d_in[16];
  const float* Wm2  = (const float*)d_in[17];
  const float* bm2  = (const float*)d_in[18];
  const float* Wm3  = (const float*)d_in[19];
  const float* bm3  = (const float*)d_in[20];
  float* out = (float*)d_out;

  const int N = in_sizes[0] / 128;
  const int E = in_sizes[3];

  char* w = (char*)d_ws;
  auto alloc = [&](size_t bytes) -> char* {
    char* p = w;
    w += (bytes + 255) & ~(size_t)255;
    return p;
  };
  int* deg   = (int*)alloc((size_t)N * 4);
  int* off   = (int*)alloc((size_t)(N + 1) * 4);
  int* cur   = (int*)alloc((size_t)N * 4);
  int* elist = (int*)alloc((size_t)E * 4);
  unsigned short* Pm  = (unsigned short*)alloc((size_t)N * 64 * 2);   // bf16 msg table
  float*          Xr  = (float*)alloc((size_t)N * 64 * 4);            // f32 lin_r part
  unsigned short* UVb = (unsigned short*)alloc((size_t)N * 128 * 2);  // bf16 u|v table
  float* HP       = (float*)alloc((size_t)N * 64 * 4);
  float* partials = (float*)alloc(256 * 128 * 4);
  float* sc1 = (float*)alloc(64 * 4);
  float* sh1 = (float*)alloc(64 * 4);
  float* sc2 = (float*)alloc(64 * 4);
  float* sh2 = (float*)alloc(64 * 4);
  unsigned short* blob = (unsigned short*)alloc(4096 * 2);
  int* bsum  = (int*)alloc(256 * 4);

  const int* srcp = ei;
  const int* dstp = ei + E;

  int eb = (E + 255) / 256;
  int nb4 = (N + 3) / 4;
  int nb64 = (N + 63) / 64;
  int sb = (N + 1023) / 1024;

  // CSR build (shared by both SAGE layers)
  hipMemsetAsync(deg, 0, (size_t)N * 4, stream);
  hipLaunchKernelGGL(hist_kernel, dim3(eb), dim3(256), 0, stream, dstp, E, deg);
  hipLaunchKernelGGL(scan_blocks_kernel, dim3(sb), dim3(1024), 0, stream, deg, N, off, bsum);
  hipLaunchKernelGGL(scan_sums_kernel, dim3(1), dim3(64), 0, stream, bsum, sb);
  hipLaunchKernelGGL(scan_add_kernel, dim3(sb), dim3(1024), 0, stream, bsum, N, off, cur);
  hipLaunchKernelGGL(fill_kernel, dim3(eb), dim3(256), 0, stream, srcp, dstp, E, cur, elist);

  // ---- SAGE layer 1 ----
  hipLaunchKernelGGL((proj2_kernel<128, false, 0>), dim3(nb64, 2), dim3(256), 0, stream,
                     x, W1l, 128, 0, W1r, 128, 0, (const float*)nullptr, (const float*)nullptr,
                     (void*)Pm, (void*)Xr, N);
  hipLaunchKernelGGL(agg_kernel, dim3(nb4), dim3(256), 0, stream, Pm, Xr, off, deg, elist, b1l, HP, N);
  hipLaunchKernelGGL(stats_kernel, dim3(256), dim3(256), 0, stream, HP, N, partials);
  hipLaunchKernelGGL(bn_finalize_kernel, dim3(1), dim3(64), 0, stream, partials, 256, N, g1, be1, sc1, sh1);

  // ---- SAGE layer 2 (BN1+relu fused into projection load) ----
  hipLaunchKernelGGL((proj2_kernel<64, true, 0>), dim3(nb64, 2), dim3(256), 0, stream,
                     HP, W2l, 64, 0, W2r, 64, 0, sc1, sh1, (void*)Pm, (void*)Xr, N);
  hipLaunchKernelGGL(agg_kernel, dim3(nb4), dim3(256), 0, stream, Pm, Xr, off, deg, elist, b2l, HP, N);
  hipLaunchKernelGGL(stats_kernel, dim3(256), dim3(256), 0, stream, HP, N, partials);
  hipLaunchKernelGGL(bn_finalize_kernel, dim3(1), dim3(64), 0, stream, partials, 256, N, g2, be2, sc2, sh2);

  // ---- u/v node precompute + weight packing ----
  hipLaunchKernelGGL((proj2_kernel<64, true, 1>), dim3(nb64, 2), dim3(256), 0, stream,
                     HP, Wm1, 152, 0, Wm1, 152, 64, sc2, sh2, (void*)UVb, (void*)nullptr, N);
  hipLaunchKernelGGL(prep_kernel, dim3(1), dim3(256), 0, stream, Wm1, temb, bm1, Wm2, blob);

  // ---- fused edge MLP (wave-local MFMA, zero-staging) ----
  int ebm = (E + 63) / 64;
  hipLaunchKernelGGL(edge_mfma_kernel, dim3(ebm), dim3(64), 0, stream,
                     UVb, ei, ea, tix, blob, Wm3, bm2, bm3, out, E);
}

// Round 8
// 613.644 us; speedup vs baseline: 1.4067x; 1.1372x over previous
//
#include <hip/hip_runtime.h>

constexpr float BN_EPS = 1e-5f;

typedef __attribute__((ext_vector_type(8))) short bf16x8;
typedef __attribute__((ext_vector_type(4))) float f32x4;

__device__ __forceinline__ float4 ld4(const float* p) { return *(const float4*)p; }
__device__ __forceinline__ unsigned short f2bf(float x) {
  union { float f; unsigned u; } c; c.f = x;
  unsigned r = (c.u + 0x7fffu + ((c.u >> 16) & 1u)) >> 16;
  return (unsigned short)r;
}
__device__ __forceinline__ float bf1(unsigned short h) {
  union { unsigned i; float f; } a; a.i = ((unsigned)h) << 16; return a.f;
}
__device__ __forceinline__ float2 bf2(unsigned u) {
  union { unsigned i; float f; } lo, hi;
  lo.i = u << 16; hi.i = u & 0xffff0000u;
  return make_float2(lo.f, hi.f);
}
// packed f32->bf16 (RNE), 1 instr for 2 values
__device__ __forceinline__ unsigned pk_bf16(float lo, float hi) {
  unsigned r;
  asm("v_cvt_pk_bf16_f32 %0, %1, %2" : "=v"(r) : "v"(lo), "v"(hi));
  return r;
}

// ---------------- CSR build (R6 version — post-timing-replay stable) ----------------
__global__ void hist_kernel(const int* __restrict__ dst, int E, int* __restrict__ deg) {
  int e = blockIdx.x * 256 + threadIdx.x;
  if (e < E) atomicAdd(&deg[dst[e]], 1);
}

__global__ __launch_bounds__(1024) void scan_blocks_kernel(const int* __restrict__ deg, int n,
                                                           int* __restrict__ off, int* __restrict__ bsum) {
  __shared__ int lds[1024];
  int i = blockIdx.x * 1024 + threadIdx.x;
  int v = (i < n) ? deg[i] : 0;
  lds[threadIdx.x] = v;
  __syncthreads();
  for (int s = 1; s < 1024; s <<= 1) {
    int t = (threadIdx.x >= (unsigned)s) ? lds[threadIdx.x - s] : 0;
    __syncthreads();
    lds[threadIdx.x] += t;
    __syncthreads();
  }
  if (i < n) off[i] = lds[threadIdx.x] - v;
  if (threadIdx.x == 1023) bsum[blockIdx.x] = lds[1023];
}

__global__ void scan_sums_kernel(int* __restrict__ bsum, int nb) {
  int carry = 0;
  for (int base = 0; base < nb; base += 64) {
    int l = base + (int)threadIdx.x;
    int orig = (l < nb) ? bsum[l] : 0;
    int v = orig;
    for (int s = 1; s < 64; s <<= 1) {
      int t = __shfl_up(v, s);
      if ((int)threadIdx.x >= s) v += t;
    }
    if (l < nb) bsum[l] = carry + v - orig;
    carry += __shfl(v, 63);
  }
}

__global__ __launch_bounds__(1024) void scan_add_kernel(const int* __restrict__ bsum, int n,
                                                        int* __restrict__ off, int* __restrict__ cur) {
  int i = blockIdx.x * 1024 + threadIdx.x;
  if (i < n) {
    int o = off[i] + bsum[blockIdx.x];
    off[i] = o;
    cur[i] = o;
  }
}

__global__ void fill_kernel(const int* __restrict__ src, const int* __restrict__ dst, int E,
                            int* __restrict__ cur, int* __restrict__ elist) {
  int e = blockIdx.x * 256 + threadIdx.x;
  if (e < E) {
    int p = atomicAdd(&cur[dst[e]], 1);
    elist[p] = src[e];
  }
}

// ---------------- node projection via MFMA ----------------
// Block: 64 nodes x 64 outputs; blockIdx.y = output half (Wa / Wb).
// 4 waves; wave w owns nodes [w*16, w*16+16). x and W staged as bf16 in LDS.
// Pitch KP shorts (K+4): row stride 264B/136B -> 8B aligned (b64 reads),
// bank word index = 2*c16 + 4*g (mod 32) -> <=2-way alias (free).
// MFMA 16x16x32 bf16, fragment maps per m89 (same as edge kernel).
// MODE 0: ob=0 -> bf16 outA[N,64]; ob=1 -> f32 outB[N,64]
// MODE 1: both halves -> bf16 outA[N,128] at col ob*64+...
template <int K, bool BN, int MODE>
__global__ __launch_bounds__(256) void proj3_kernel(
    const float* __restrict__ X,
    const float* __restrict__ Wa, int lda, int koffa,
    const float* __restrict__ Wb, int ldb, int koffb,
    const float* __restrict__ scale, const float* __restrict__ shift,
    void* __restrict__ outA, void* __restrict__ outB, int n) {
  constexpr int KP = K + 4;
  __shared__ alignas(16) unsigned short ws[64 * KP];
  __shared__ alignas(16) unsigned short xs[64 * KP];
  const int ob = blockIdx.y;
  const float* W = ob ? Wb : Wa;
  const int ld = ob ? ldb : lda;
  const int koff = ob ? koffb : koffa;
  const int tid = threadIdx.x;

  for (int idx = tid; idx < 64 * K; idx += 256) {
    int o = idx / K, k = idx - o * K;
    ws[o * KP + k] = f2bf(W[o * ld + koff + k]);
  }
  const int nb = blockIdx.x * 64;
  for (int idx = tid; idx < 64 * K; idx += 256) {
    int nl = idx / K, k = idx - nl * K;
    int node = nb + nl;
    float v = (node < n) ? X[(size_t)node * K + k] : 0.f;
    if (BN) v = fmaxf(fmaf(v, scale[k], shift[k]), 0.f);
    xs[nl * KP + k] = f2bf(v);
  }
  __syncthreads();

  const int w = tid >> 6, lane = tid & 63;
  const int g = lane >> 4, c16 = lane & 15;

  f32x4 acc[4];
#pragma unroll
  for (int ct = 0; ct < 4; ++ct) acc[ct] = f32x4{0.f, 0.f, 0.f, 0.f};

  const unsigned short* xrow = &xs[(w * 16 + c16) * KP];
#pragma unroll
  for (int ks = 0; ks < K / 32; ++ks) {
    union { bf16x8 v; uint2 u[2]; } a;
    a.u[0] = *(const uint2*)(xrow + ks * 32 + g * 8);
    a.u[1] = *(const uint2*)(xrow + ks * 32 + g * 8 + 4);
#pragma unroll
    for (int ct = 0; ct < 4; ++ct) {
      union { bf16x8 v; uint2 u[2]; } b;
      const unsigned short* wrow = &ws[(ct * 16 + c16) * KP + ks * 32 + g * 8];
      b.u[0] = *(const uint2*)(wrow);
      b.u[1] = *(const uint2*)(wrow + 4);
      acc[ct] = __builtin_amdgcn_mfma_f32_16x16x32_bf16(a.v, b.v, acc[ct], 0, 0, 0);
    }
  }

  // C/D: col = ct*16 + c16, node = nb + w*16 + g*4 + r
#pragma unroll
  for (int ct = 0; ct < 4; ++ct) {
    int col = ct * 16 + c16;
#pragma unroll
    for (int r = 0; r < 4; ++r) {
      int node = nb + w * 16 + g * 4 + r;
      if (node < n) {
        float v = acc[ct][r];
        if (MODE == 0) {
          if (ob == 0) ((unsigned short*)outA)[(size_t)node * 64 + col] = f2bf(v);
          else         ((float*)outB)[(size_t)node * 64 + col] = v;
        } else {
          ((unsigned short*)outA)[(size_t)node * 128 + ob * 64 + col] = f2bf(v);
        }
      }
    }
  }
}

// ---------------- aggregation ----------------
__global__ __launch_bounds__(256) void agg_kernel(
    const unsigned short* __restrict__ Pm, const float* __restrict__ Xr,
    const int* __restrict__ off, const int* __restrict__ deg,
    const int* __restrict__ elist, const float* __restrict__ bl,
    float* __restrict__ HP, int n) {
  int node = blockIdx.x * 4 + (threadIdx.x >> 6);
  if (node >= n) return;
  int c = threadIdx.x & 63;
  int d = deg[node];
  int o = off[node];
  float a0 = 0.f, a1 = 0.f, a2 = 0.f, a3 = 0.f;
  float a4 = 0.f, a5 = 0.f, a6 = 0.f, a7 = 0.f;
  int j = 0;
  for (; j + 8 <= d; j += 8) {
    int s0 = elist[o + j + 0], s1 = elist[o + j + 1], s2 = elist[o + j + 2], s3 = elist[o + j + 3];
    int s4 = elist[o + j + 4], s5 = elist[o + j + 5], s6 = elist[o + j + 6], s7 = elist[o + j + 7];
    a0 += bf1(Pm[(size_t)s0 * 64 + c]);
    a1 += bf1(Pm[(size_t)s1 * 64 + c]);
    a2 += bf1(Pm[(size_t)s2 * 64 + c]);
    a3 += bf1(Pm[(size_t)s3 * 64 + c]);
    a4 += bf1(Pm[(size_t)s4 * 64 + c]);
    a5 += bf1(Pm[(size_t)s5 * 64 + c]);
    a6 += bf1(Pm[(size_t)s6 * 64 + c]);
    a7 += bf1(Pm[(size_t)s7 * 64 + c]);
  }
  for (; j < d; ++j) a0 += bf1(Pm[(size_t)elist[o + j] * 64 + c]);
  float acc = ((a0 + a1) + (a2 + a3)) + ((a4 + a5) + (a6 + a7));
  float agg = acc / (float)(d > 0 ? d : 1);
  HP[(size_t)node * 64 + c] = agg + bl[c] + Xr[(size_t)node * 64 + c];
}

// ---------------- BN statistics ----------------
__global__ __launch_bounds__(256) void stats_kernel(const float* __restrict__ HP, int n,
                                                    float* __restrict__ partials) {
  int c = threadIdx.x & 63;
  int r0 = blockIdx.x * 4 + (threadIdx.x >> 6);
  float s = 0.f, q = 0.f;
  for (int i = r0; i < n; i += 1024) {
    float v = HP[(size_t)i * 64 + c];
    s += v; q += v * v;
  }
  __shared__ float ls[256], lq[256];
  ls[threadIdx.x] = s; lq[threadIdx.x] = q;
  __syncthreads();
  if (threadIdx.x < 64) {
    s = ls[threadIdx.x] + ls[threadIdx.x + 64] + ls[threadIdx.x + 128] + ls[threadIdx.x + 192];
    q = lq[threadIdx.x] + lq[threadIdx.x + 64] + lq[threadIdx.x + 128] + lq[threadIdx.x + 192];
    partials[blockIdx.x * 128 + c] = s;
    partials[blockIdx.x * 128 + 64 + c] = q;
  }
}

__global__ void bn_finalize_kernel(const float* __restrict__ partials, int nblk, int n,
                                   const float* __restrict__ g, const float* __restrict__ be,
                                   float* __restrict__ scale, float* __restrict__ shift) {
  int c = threadIdx.x;  // 64 threads
  float s = 0.f, q = 0.f;
  for (int b = 0; b < nblk; ++b) { s += partials[b * 128 + c]; q += partials[b * 128 + 64 + c]; }
  float mean = s / (float)n;
  float var = q / (float)n - mean * mean;
  float sc = g[c] * rsqrtf(var + BN_EPS);
  scale[c] = sc;
  shift[c] = be[c] - mean * sc;
}

// ---------------- prep: pack edge-MLP weights to bf16 blob ----------------
// blob[0:2048)   = B1[o=64][k=32]: k<16 -> Cw[k][o]=Wm1[o][128+k]; k>=16 -> Dte[k-16][o] (incl bm1)
// blob[2048:4096) = W2[j=32][k=64]
__global__ void prep_kernel(const float* __restrict__ Wm1, const float* __restrict__ temb,
                            const float* __restrict__ bm1, const float* __restrict__ Wm2,
                            unsigned short* __restrict__ blob) {
  for (int i = threadIdx.x; i < 2048; i += 256) {
    int o = i >> 5, k = i & 31;
    float v;
    if (k < 16) {
      v = Wm1[o * 152 + 128 + k];
    } else {
      int t = k - 16;
      v = bm1[o];
#pragma unroll
      for (int q = 0; q < 8; ++q) v = fmaf(Wm1[o * 152 + 144 + q], temb[t * 8 + q], v);
    }
    blob[o * 32 + k] = f2bf(v);
  }
  for (int i = threadIdx.x; i < 2048; i += 256) {
    int j = i >> 6, k = i & 63;
    blob[2048 + j * 64 + k] = f2bf(Wm2[j * 64 + k]);
  }
}

// ---------------- fused edge MLP via MFMA, wave-local, zero-staging ----------------
// 64 edges per 64-thread (1-wave) block. LDS only holds the z1 tile (8.4KB),
// col-major [64 o][64 e] pitch 66 shorts.
// z1 = relu( [ea|onehot_t] @ [Cw;Dte]^T + I·u[s] + I·v[d] )
// z2 = relu( bm2 + z1 @ W2^T );  out = bm3 + z2 @ W3^T
__global__ __launch_bounds__(64, 4) void edge_mfma_kernel(
    const unsigned short* __restrict__ UVb, const int* __restrict__ ei,
    const float* __restrict__ eattr, const int* __restrict__ tix,
    const unsigned short* __restrict__ blob,
    const float* __restrict__ Wm3, const float* __restrict__ bm2,
    const float* __restrict__ bm3, float* __restrict__ out, int E) {
  constexpr int P = 66;                       // shorts per column (33 words, odd -> bank spread)
  __shared__ unsigned short z1T[64 * P];
  unsigned* z1T32 = (unsigned*)z1T;

  const int tid = threadIdx.x;
  const int g = tid >> 4, c16 = tid & 15;
  const int base = blockIdx.x * 64;

  // ---- B fragments straight from global (L2 broadcast, no LDS) ----
  bf16x8 bfr[4];
#pragma unroll
  for (int ct = 0; ct < 4; ++ct)
    bfr[ct] = *(const bf16x8*)(blob + (ct * 16 + c16) * 32 + g * 8);
  bf16x8 bw[2][2];
  const unsigned short* w2b = blob + 2048;
#pragma unroll
  for (int jt = 0; jt < 2; ++jt)
#pragma unroll
    for (int ks = 0; ks < 2; ++ks)
      bw[jt][ks] = *(const bf16x8*)(w2b + (jt * 16 + c16) * 64 + ks * 32 + g * 8);
  // identity B fragments: bi[h].s8[j] = (k_local==16h+c16) ? 1.0bf16 : 0
  union { bf16x8 v; short s8[8]; } bi0, bi1;
#pragma unroll
  for (int j = 0; j < 8; ++j) {
    bi0.s8[j] = (g * 8 + j == c16) ? (short)0x3F80 : (short)0;
    bi1.s8[j] = (g * 8 + j == 16 + c16) ? (short)0x3F80 : (short)0;
  }
  const float bm2c0 = bm2[c16], bm2c1 = bm2[16 + c16];
  const float2 w3c0 = make_float2(Wm3[c16], Wm3[32 + c16]);
  const float2 w3c1 = make_float2(Wm3[16 + c16], Wm3[48 + c16]);
  const float b3a = bm3[0], b3b = bm3[1];

  // ---- phase A: z1 tiles (u/v gathered straight into A-fragments) ----
#pragma unroll
  for (int et = 0; et < 4; ++et) {
    int erow = base + et * 16 + c16;            // this lane's A-row edge
    bool lv = erow < E;
    int s = lv ? ei[erow] : 0;
    int d = lv ? ei[E + erow] : 0;
    // A_eaoh: k<16 = ea, k>=16 = onehot(t)
    bf16x8 a_eaoh;
    if (g < 2) {
      if (lv) {
        const float* eap = eattr + (size_t)erow * 16 + g * 8;
        float4 f0 = ld4(eap), f1 = ld4(eap + 4);
        union { bf16x8 v; unsigned u[4]; } cc;
        cc.u[0] = pk_bf16(f0.x, f0.y); cc.u[1] = pk_bf16(f0.z, f0.w);
        cc.u[2] = pk_bf16(f1.x, f1.y); cc.u[3] = pk_bf16(f1.z, f1.w);
        a_eaoh = cc.v;
      } else {
        a_eaoh = bf16x8{0, 0, 0, 0, 0, 0, 0, 0};
      }
    } else {
      int t = lv ? tix[erow] : -1;
      int kb = (g - 2) * 8;
      union { bf16x8 v; short s8[8]; } cc;
#pragma unroll
      for (int j = 0; j < 8; ++j) cc.s8[j] = (t == kb + j) ? (short)0x3F80 : (short)0;
      a_eaoh = cc.v;
    }
    // u/v A-fragments: row e, k window w covers u-elems [32w,32w+32)
    const bf16x8* urow = (const bf16x8*)(UVb + (size_t)s * 128);
    const bf16x8* vrow = (const bf16x8*)(UVb + (size_t)d * 128);
    bf16x8 au0 = urow[g];         // u elems g*8..g*8+8      (window 0)
    bf16x8 au1 = urow[4 + g];     // u elems 32+g*8..        (window 1)
    bf16x8 av0 = vrow[8 + g];     // v elems g*8..           (window 0)
    bf16x8 av1 = vrow[12 + g];    // v elems 32+g*8..        (window 1)

#pragma unroll
    for (int ct = 0; ct < 4; ++ct) {
      f32x4 acc = {0.f, 0.f, 0.f, 0.f};
      acc = __builtin_amdgcn_mfma_f32_16x16x32_bf16(a_eaoh, bfr[ct], acc, 0, 0, 0);
      const bf16x8 au = (ct < 2) ? au0 : au1;
      const bf16x8 av = (ct < 2) ? av0 : av1;
      const bf16x8 bi = (ct & 1) ? bi1.v : bi0.v;
      acc = __builtin_amdgcn_mfma_f32_16x16x32_bf16(au, bi, acc, 0, 0, 0);
      acc = __builtin_amdgcn_mfma_f32_16x16x32_bf16(av, bi, acc, 0, 0, 0);
      int cw = (ct * 16 + c16) * 33 + et * 8 + g * 2;
      z1T32[cw]     = pk_bf16(fmaxf(acc[0], 0.f), fmaxf(acc[1], 0.f));
      z1T32[cw + 1] = pk_bf16(fmaxf(acc[2], 0.f), fmaxf(acc[3], 0.f));
    }
  }
  __syncthreads();   // single wave: orders LDS writes before reads

  // ---- phase B: z2 + z3 ----
#pragma unroll
  for (int et = 0; et < 4; ++et) {
    int ecol = et * 16 + c16;                   // this lane's A-row (edge, local)
    union { bf16x8 v; unsigned short s8[8]; } A0, A1;
#pragma unroll
    for (int j = 0; j < 8; ++j) {
      A0.s8[j] = z1T[(g * 8 + j) * P + ecol];        // z1[e][k], k = g*8+j
      A1.s8[j] = z1T[(32 + g * 8 + j) * P + ecol];   // k = 32+g*8+j
    }
    f32x4 p0 = {0.f, 0.f, 0.f, 0.f}, p1 = {0.f, 0.f, 0.f, 0.f};
#pragma unroll
    for (int jt = 0; jt < 2; ++jt) {
      float bm = jt ? bm2c1 : bm2c0;
      float2 w3 = jt ? w3c1 : w3c0;
      f32x4 acc = {bm, bm, bm, bm};
      acc = __builtin_amdgcn_mfma_f32_16x16x32_bf16(A0.v, bw[jt][0], acc, 0, 0, 0);
      acc = __builtin_amdgcn_mfma_f32_16x16x32_bf16(A1.v, bw[jt][1], acc, 0, 0, 0);
#pragma unroll
      for (int r = 0; r < 4; ++r) {
        float z = fmaxf(acc[r], 0.f);
        p0[r] = fmaf(z, w3.x, p0[r]);
        p1[r] = fmaf(z, w3.y, p1[r]);
      }
    }
#pragma unroll
    for (int m = 1; m < 16; m <<= 1) {
#pragma unroll
      for (int r = 0; r < 4; ++r) {
        p0[r] += __shfl_xor(p0[r], m, 16);
        p1[r] += __shfl_xor(p1[r], m, 16);
      }
    }
    if (c16 == 0) {
      int eo = base + et * 16 + g * 4;
      if (eo + 3 < E) {
        float4 f0 = make_float4(p0[0] + b3a, p1[0] + b3b, p0[1] + b3a, p1[1] + b3b);
        float4 f1 = make_float4(p0[2] + b3a, p1[2] + b3b, p0[3] + b3a, p1[3] + b3b);
        *(float4*)&out[(size_t)eo * 2] = f0;
        *(float4*)&out[(size_t)eo * 2 + 4] = f1;
      } else {
#pragma unroll
        for (int r = 0; r < 4; ++r) {
          if (eo + r < E) {
            out[(size_t)(eo + r) * 2] = p0[r] + b3a;
            out[(size_t)(eo + r) * 2 + 1] = p1[r] + b3b;
          }
        }
      }
    }
  }
}

// ---------------- launcher ----------------
extern "C" void kernel_launch(void* const* d_in, const int* in_sizes, int n_in,
                              void* d_out, int out_size, void* d_ws, size_t ws_size,
                              hipStream_t stream) {
  const float* x    = (const float*)d_in[0];
  const int*   ei   = (const int*)d_in[1];
  const float* ea   = (const float*)d_in[2];
  const int*   tix  = (const int*)d_in[3];
  const float* temb = (const float*)d_in[4];
  const float* W1l  = (const float*)d_in[5];
  const float* b1l  = (const float*)d_in[6];
  const float* W1r  = (const float*)d_in[7];
  const float* g1   = (const float*)d_in[8];
  const float* be1  = (const float*)d_in[9];
  const float* W2l  = (const float*)d_in[10];
  const float* b2l  = (const float*)d_in[11];
  const float* W2r  = (const float*)d_in[12];
  const float* g2   = (const float*)d_in[13];
  const float* be2  = (const float*)d_in[14];
  const float* Wm1  = (const float*)d_in[15];
  const float* bm1  = (const float*)d_in[16];
  const float* Wm2  = (const float*)d_in[17];
  const float* bm2  = (const float*)d_in[18];
  const float* Wm3  = (const float*)d_in[19];
  const float* bm3  = (const float*)d_in[20];
  float* out = (float*)d_out;

  const int N = in_sizes[0] / 128;
  const int E = in_sizes[3];

  char* w = (char*)d_ws;
  auto alloc = [&](size_t bytes) -> char* {
    char* p = w;
    w += (bytes + 255) & ~(size_t)255;
    return p;
  };
  int* deg   = (int*)alloc((size_t)N * 4);
  int* off   = (int*)alloc((size_t)(N + 1) * 4);
  int* cur   = (int*)alloc((size_t)N * 4);
  int* elist = (int*)alloc((size_t)E * 4);
  unsigned short* Pm  = (unsigned short*)alloc((size_t)N * 64 * 2);   // bf16 msg table
  float*          Xr  = (float*)alloc((size_t)N * 64 * 4);            // f32 lin_r part
  unsigned short* UVb = (unsigned short*)alloc((size_t)N * 128 * 2);  // bf16 u|v table
  float* HP       = (float*)alloc((size_t)N * 64 * 4);
  float* partials = (float*)alloc(256 * 128 * 4);
  float* sc1 = (float*)alloc(64 * 4);
  float* sh1 = (float*)alloc(64 * 4);
  float* sc2 = (float*)alloc(64 * 4);
  float* sh2 = (float*)alloc(64 * 4);
  unsigned short* blob = (unsigned short*)alloc(4096 * 2);
  int* bsum  = (int*)alloc(256 * 4);

  const int* srcp = ei;
  const int* dstp = ei + E;

  int eb = (E + 255) / 256;
  int nb4 = (N + 3) / 4;
  int nb64 = (N + 63) / 64;
  int sb = (N + 1023) / 1024;

  // CSR build (shared by both SAGE layers)
  hipMemsetAsync(deg, 0, (size_t)N * 4, stream);
  hipLaunchKernelGGL(hist_kernel, dim3(eb), dim3(256), 0, stream, dstp, E, deg);
  hipLaunchKernelGGL(scan_blocks_kernel, dim3(sb), dim3(1024), 0, stream, deg, N, off, bsum);
  hipLaunchKernelGGL(scan_sums_kernel, dim3(1), dim3(64), 0, stream, bsum, sb);
  hipLaunchKernelGGL(scan_add_kernel, dim3(sb), dim3(1024), 0, stream, bsum, N, off, cur);
  hipLaunchKernelGGL(fill_kernel, dim3(eb), dim3(256), 0, stream, srcp, dstp, E, cur, elist);

  // ---- SAGE layer 1 ----
  hipLaunchKernelGGL((proj3_kernel<128, false, 0>), dim3(nb64, 2), dim3(256), 0, stream,
                     x, W1l, 128, 0, W1r, 128, 0, (const float*)nullptr, (const float*)nullptr,
                     (void*)Pm, (void*)Xr, N);
  hipLaunchKernelGGL(agg_kernel, dim3(nb4), dim3(256), 0, stream, Pm, Xr, off, deg, elist, b1l, HP, N);
  hipLaunchKernelGGL(stats_kernel, dim3(256), dim3(256), 0, stream, HP, N, partials);
  hipLaunchKernelGGL(bn_finalize_kernel, dim3(1), dim3(64), 0, stream, partials, 256, N, g1, be1, sc1, sh1);

  // ---- SAGE layer 2 (BN1+relu fused into projection load) ----
  hipLaunchKernelGGL((proj3_kernel<64, true, 0>), dim3(nb64, 2), dim3(256), 0, stream,
                     HP, W2l, 64, 0, W2r, 64, 0, sc1, sh1, (void*)Pm, (void*)Xr, N);
  hipLaunchKernelGGL(agg_kernel, dim3(nb4), dim3(256), 0, stream, Pm, Xr, off, deg, elist, b2l, HP, N);
  hipLaunchKernelGGL(stats_kernel, dim3(256), dim3(256), 0, stream, HP, N, partials);
  hipLaunchKernelGGL(bn_finalize_kernel, dim3(1), dim3(64), 0, stream, partials, 256, N, g2, be2, sc2, sh2);

  // ---- u/v node precompute + weight packing ----
  hipLaunchKernelGGL((proj3_kernel<64, true, 1>), dim3(nb64, 2), dim3(256), 0, stream,
                     HP, Wm1, 152, 0, Wm1, 152, 64, sc2, sh2, (void*)UVb, (void*)nullptr, N);
  hipLaunchKernelGGL(prep_kernel, dim3(1), dim3(256), 0, stream, Wm1, temb, bm1, Wm2, blob);

  // ---- fused edge MLP (wave-local MFMA, zero-staging) ----
  int ebm = (E + 63) / 64;
  hipLaunchKernelGGL(edge_mfma_kernel, dim3(ebm), dim3(64), 0, stream,
                     UVb, ei, ea, tix, blob, Wm3, bm2, bm3, out, E);
}